// Round 12
// baseline (488.877 us; speedup 1.0000x reference)
//
#include <hip/hip_runtime.h>

#define B_ 4
#define N_ 512
#define D_ 768
#define A_ 128

typedef short bf16x8 __attribute__((ext_vector_type(8)));
typedef ushort u16x8 __attribute__((ext_vector_type(8)));
typedef float f32x4 __attribute__((ext_vector_type(4)));

__device__ __forceinline__ ushort f2h(float x) {  // f32 -> bf16 bits, RNE
  uint u = __builtin_bit_cast(uint, x);
  return (ushort)((u + 0x7fffu + ((u >> 16) & 1u)) >> 16);
}
__device__ __forceinline__ float h2f(ushort h) {
  uint u = ((uint)h) << 16;
  return __builtin_bit_cast(float, u);
}
__device__ __forceinline__ bf16x8 ld8(const ushort* p) {
  return *(const bf16x8*)p;
}
#define MFMA(a, b, c) __builtin_amdgcn_mfma_f32_16x16x32_bf16(a, b, c, 0, 0, 0)

// ---------------------------------------------------------------------------
// k0: fused prep (+ uvec = -2*v write).
// ---------------------------------------------------------------------------
__global__ __launch_bounds__(256) void k0_prep(
    const float* __restrict__ M, const float* __restrict__ W1,
    const float* __restrict__ W2, const float* __restrict__ vw,
    ushort* __restrict__ Mr_h, ushort* __restrict__ Mr_l,
    ushort* __restrict__ Mt_h, ushort* __restrict__ Mt_l,
    ushort* __restrict__ Wt_h, ushort* __restrict__ Wt_l,
    float* __restrict__ uvec) {
  __shared__ ushort lds_h[64][40];
  __shared__ ushort lds_l[64][40];
  const int t = threadIdx.x;
  const int bid = blockIdx.x;
  if (bid < 768) {  // ---- M part ----
    const int dq = bid % 12;
    const int rest = bid / 12;
    const int d0 = dq * 64;
    const int n0 = (rest & 15) * 32;
    const int b = rest >> 4;
    const int n = t >> 3;          // 0..31
    const int dg = (t & 7) * 8;    // 0..56
    const size_t roff = ((size_t)(b * N_ + n0 + n)) * D_ + d0 + dg;
    const float4 v0 = *(const float4*)(M + roff);
    const float4 v1 = *(const float4*)(M + roff + 4);
    const float x[8] = {v0.x, v0.y, v0.z, v0.w, v1.x, v1.y, v1.z, v1.w};
    u16x8 vh, vl;
#pragma unroll
    for (int e = 0; e < 8; ++e) {
      ushort h = f2h(x[e]);
      ushort l = f2h(x[e] - h2f(h));
      vh[e] = h;
      vl[e] = l;
      lds_h[dg + e][n] = h;
      lds_l[dg + e][n] = l;
    }
    *(u16x8*)(Mr_h + roff) = vh;
    *(u16x8*)(Mr_l + roff) = vl;
    __syncthreads();
    const int dd = t >> 2;          // 0..63
    const int ng = (t & 3) * 8;     // 0..24
    const size_t toff = ((size_t)b * D_ + d0 + dd) * N_ + n0 + ng;
    *(u16x8*)(Mt_h + toff) = *(const u16x8*)(&lds_h[dd][ng]);
    *(u16x8*)(Mt_l + toff) = *(const u16x8*)(&lds_l[dd][ng]);
  } else {  // ---- W part ----
    const int c = t;
    const int k0 = (bid - 768) * 8;
    const float* __restrict__ Wp = (c < A_) ? W1 : W2;
    const int cc = c & (A_ - 1);
    u16x8 vh, vl;
#pragma unroll
    for (int e = 0; e < 8; ++e) {
      float x = Wp[(size_t)(k0 + e) * A_ + cc];
      ushort h = f2h(x);
      vh[e] = h;
      vl[e] = f2h(x - h2f(h));
    }
    *(u16x8*)(Wt_h + (size_t)c * D_ + k0) = vh;
    *(u16x8*)(Wt_l + (size_t)c * D_ + k0) = vl;
    if (bid == 768 && c < A_) uvec[c] = -2.f * vw[c];
  }
}

// ---------------------------------------------------------------------------
// k1 v3: M @ [W1|W2] -> EXPONENTIALS (unchanged).
// ---------------------------------------------------------------------------
__global__ __launch_bounds__(256) void k1_mfma(
    const ushort* __restrict__ Mr_h, const ushort* __restrict__ Mr_l,
    const ushort* __restrict__ Wt_h, const ushort* __restrict__ Wt_l,
    const float* __restrict__ b1, const float* __restrict__ b2,
    float* __restrict__ w1e, float* __restrict__ w2e) {
  __shared__ float l_red[4][32][33];  // 16.9 KB
  const int t = threadIdx.x;
  const int l = t & 63;
  const int w = t >> 6;
  const int r = l & 15, g = l >> 4;
  const int row0 = blockIdx.x * 32;
  const int cb = blockIdx.y * 32;
  const int kbase = w * 192;  // wave-private K-range (6 K-steps of 32)
  const size_t oA = (size_t)(row0 + r) * D_ + kbase + g * 8;
  const size_t oA2 = oA + (size_t)16 * D_;
  const size_t oB = (size_t)(cb + r) * D_ + kbase + g * 8;
  const size_t oB2 = oB + (size_t)16 * D_;
  f32x4 acc[2][2] = {};
  bf16x8 A[2][4], Bv[2][4];
#define K1LOAD(s, k0)                                                        \
  A[s][0] = ld8(Mr_h + oA + (k0));  A[s][1] = ld8(Mr_h + oA2 + (k0));        \
  A[s][2] = ld8(Mr_l + oA + (k0));  A[s][3] = ld8(Mr_l + oA2 + (k0));        \
  Bv[s][0] = ld8(Wt_h + oB + (k0)); Bv[s][1] = ld8(Wt_h + oB2 + (k0));       \
  Bv[s][2] = ld8(Wt_l + oB + (k0)); Bv[s][3] = ld8(Wt_l + oB2 + (k0));
#define K1MM(s)                                                              \
  acc[0][0] = MFMA(A[s][0], Bv[s][0], acc[0][0]);                            \
  acc[0][0] = MFMA(A[s][0], Bv[s][2], acc[0][0]);                            \
  acc[0][0] = MFMA(A[s][2], Bv[s][0], acc[0][0]);                            \
  acc[0][1] = MFMA(A[s][0], Bv[s][1], acc[0][1]);                            \
  acc[0][1] = MFMA(A[s][0], Bv[s][3], acc[0][1]);                            \
  acc[0][1] = MFMA(A[s][2], Bv[s][1], acc[0][1]);                            \
  acc[1][0] = MFMA(A[s][1], Bv[s][0], acc[1][0]);                            \
  acc[1][0] = MFMA(A[s][1], Bv[s][2], acc[1][0]);                            \
  acc[1][0] = MFMA(A[s][3], Bv[s][0], acc[1][0]);                            \
  acc[1][1] = MFMA(A[s][1], Bv[s][1], acc[1][1]);                            \
  acc[1][1] = MFMA(A[s][1], Bv[s][3], acc[1][1]);                            \
  acc[1][1] = MFMA(A[s][3], Bv[s][1], acc[1][1]);
  K1LOAD(0, 0)
#pragma unroll
  for (int kt = 0; kt < 6; ++kt) {
    if (kt & 1) {
      if (kt < 5) { K1LOAD(0, (kt + 1) * 32) }
      K1MM(1)
    } else {
      if (kt < 5) { K1LOAD(1, (kt + 1) * 32) }
      K1MM(0)
    }
  }
#undef K1LOAD
#undef K1MM
#pragma unroll
  for (int fi = 0; fi < 2; ++fi)
#pragma unroll
    for (int fj = 0; fj < 2; ++fj)
#pragma unroll
      for (int rr = 0; rr < 4; ++rr)
        l_red[w][fi * 16 + g * 4 + rr][fj * 16 + r] = acc[fi][fj][rr];
  __syncthreads();

  const float SC = 2.8853900817779268f;  // 2*log2(e): e^{2x} = 2^{SC*x}
  const int b = row0 >> 9;
  const int n0 = row0 & (N_ - 1);
  if (cb < A_) {  // E1: w1e[row][col], col-fast coalesced
#pragma unroll
    for (int k = 0; k < 4; ++k) {
      const int row = (t >> 5) + k * 8;
      const int col = t & 31;
      float v = l_red[0][row][col] + l_red[1][row][col] +
                l_red[2][row][col] + l_red[3][row][col];
      v = (v + b1[cb + col]) * SC;
      w1e[(size_t)(row0 + row) * A_ + cb + col] = __builtin_amdgcn_exp2f(v);
    }
  } else {  // E2: w2e[(b*128 + a)*512 + n], row(n)-fast coalesced
#pragma unroll
    for (int k = 0; k < 4; ++k) {
      const int row = t & 31;
      const int col = (t >> 5) + k * 8;
      float v = l_red[0][row][col] + l_red[1][row][col] +
                l_red[2][row][col] + l_red[3][row][col];
      v = (v + b2[cb - A_ + col]) * SC;
      w2e[(size_t)(b * A_ + cb - A_ + col) * N_ + n0 + row] =
          __builtin_amdgcn_exp2f(v);
    }
  }
}

// ---------------------------------------------------------------------------
// k2 v12: LOOP INTERCHANGE — a-chunk outer (8 chunks of 16 a), all 512 j
// inner. E2 staged as [16 a][512 j] tiles (same bytes/barriers as before).
// E1/u loads drop 8x: per chunk only 8 VMEM b128 (uniform-addr, L1-hot,
// vmcnt-counted -> decoupled from ds_read lgkmcnt; prefetched under jt0).
// Inner: {4 ds_read_b32, fma, rcp, fma} with 8 independent per-jt score
// accumulators (deep ILP). Masks hoisted. score = vs + sum_a u_a*rcp(g).
// ---------------------------------------------------------------------------
__global__ __launch_bounds__(512) void k2_scores(
    const float* __restrict__ w1e, const float* __restrict__ w2e,
    const float* __restrict__ uvec, const int* __restrict__ mask,
    const float* __restrict__ vw, ushort* __restrict__ ah,
    ushort* __restrict__ al) {
  __shared__ float l_w2[2][16][N_];  // 64 KB: [buf][a_local][j]
  const int t = threadIdx.x;
  const int lane = t & 63;
  const int w = t >> 6;
  const int i0 = blockIdx.x * 8;
  const int b = i0 >> 9;
  const int i = i0 + w;
  const float* __restrict__ w1row = w1e + (size_t)i * A_;  // uniform addr/wave

  float vs = vw[lane] + vw[64 + lane];  // Vsum via butterfly
#pragma unroll
  for (int off = 32; off; off >>= 1) vs += __shfl_xor(vs, off);

  int mk[8];
#pragma unroll
  for (int jt = 0; jt < 8; ++jt)
    mk[jt] = mask[(size_t)i * N_ + jt * 64 + lane];

  const float* __restrict__ w2src = w2e + (size_t)b * A_ * N_;
  float4 st[4];  // staging: tile = 16 a x 512 j = 2048 f4 / 512 thr

#define STAGE_LOAD(cc)                                                      \
  {                                                                         \
    const float* __restrict__ src = w2src + (size_t)(cc) * 16 * N_;         \
    _Pragma("unroll") for (int k = 0; k < 4; ++k) {                         \
      const int f = t + k * 512;                                            \
      st[k] = *(const float4*)(src + (size_t)(f >> 7) * N_ + (f & 127) * 4);\
    }                                                                       \
  }
#define STAGE_WRITE(bf)                                                     \
  {                                                                         \
    _Pragma("unroll") for (int k = 0; k < 4; ++k) {                         \
      const int f = t + k * 512;                                            \
      *(float4*)(&l_w2[bf][f >> 7][(f & 127) * 4]) = st[k];                 \
    }                                                                       \
  }

  STAGE_LOAD(0)
  STAGE_WRITE(0)
  __syncthreads();

  float s[8] = {};
#pragma unroll
  for (int cc = 0; cc < 8; ++cc) {
    if (cc + 1 < 8) STAGE_LOAD(cc + 1)  // issue early (T14)
    // hoisted broadcasts: 16 a's worth of E1 and u (8 VMEM b128, L1-hot)
    float4 waq[4], uuq[4];
#pragma unroll
    for (int aa = 0; aa < 4; ++aa) {
      waq[aa] = *(const float4*)(w1row + cc * 16 + aa * 4);
      uuq[aa] = *(const float4*)(uvec + cc * 16 + aa * 4);
    }
    const float(*wb)[N_] = l_w2[cc & 1];
#pragma unroll
    for (int aa = 0; aa < 4; ++aa) {
      const float4 wa = waq[aa];
      const float4 uu = uuq[aa];
#pragma unroll
      for (int jt = 0; jt < 8; ++jt) {
        const int jj = jt * 64 + lane;
        const float x0 = wb[aa * 4 + 0][jj];
        const float x1 = wb[aa * 4 + 1][jj];
        const float x2 = wb[aa * 4 + 2][jj];
        const float x3 = wb[aa * 4 + 3][jj];
        float acc = s[jt];
        acc = fmaf(uu.x, __builtin_amdgcn_rcpf(fmaf(wa.x, x0, 1.f)), acc);
        acc = fmaf(uu.y, __builtin_amdgcn_rcpf(fmaf(wa.y, x1, 1.f)), acc);
        acc = fmaf(uu.z, __builtin_amdgcn_rcpf(fmaf(wa.z, x2, 1.f)), acc);
        acc = fmaf(uu.w, __builtin_amdgcn_rcpf(fmaf(wa.w, x3, 1.f)), acc);
        s[jt] = acc;
      }
    }
    if (cc + 1 < 8) { STAGE_WRITE((cc + 1) & 1) }  // write late (T14)
    __syncthreads();
  }
#undef STAGE_LOAD
#undef STAGE_WRITE

  const float NEG = -3.402823466e38f;  // np.finfo(f32).min
#pragma unroll
  for (int jt = 0; jt < 8; ++jt) s[jt] = mk[jt] ? (vs + s[jt]) : NEG;

  // fused softmax: 8 regs x 64 lanes = full row per wave
  float rmax = s[0];
#pragma unroll
  for (int jt = 1; jt < 8; ++jt) rmax = fmaxf(rmax, s[jt]);
#pragma unroll
  for (int off = 32; off; off >>= 1) rmax = fmaxf(rmax, __shfl_xor(rmax, off));
  const float L2E = 1.4426950408889634f;
  float psum = 0.f;
#pragma unroll
  for (int jt = 0; jt < 8; ++jt) {
    // all-masked row: s-rmax = 0 -> 1 -> uniform 1/512 (ref match);
    // masked in live row: (NEG-rmax)*L2E -> -inf -> exp2 = 0 exactly.
    s[jt] = __builtin_amdgcn_exp2f((s[jt] - rmax) * L2E);
    psum += s[jt];
  }
#pragma unroll
  for (int off = 32; off; off >>= 1) psum += __shfl_xor(psum, off);
  const float inv = __builtin_amdgcn_rcpf(psum);
#pragma unroll
  for (int jt = 0; jt < 8; ++jt) {
    const float pv = s[jt] * inv;
    const ushort hh = f2h(pv);
    ah[(size_t)i * N_ + jt * 64 + lane] = hh;
    al[(size_t)i * N_ + jt * 64 + lane] = f2h(pv - h2f(hh));
  }
}

// ---------------------------------------------------------------------------
// k3 v4: out[b] = attn[b] @ M[b] (unchanged).
// ---------------------------------------------------------------------------
__global__ __launch_bounds__(256) void k3_mfma(
    const ushort* __restrict__ ah, const ushort* __restrict__ al,
    const ushort* __restrict__ Mt_h, const ushort* __restrict__ Mt_l,
    float* __restrict__ out) {
  __shared__ float l_red[4][64][33];  // 33.8 KB
  const int t = threadIdx.x;
  const int l = t & 63;
  const int w = t >> 6;
  const int r = l & 15, g = l >> 4;
  const int row0 = blockIdx.x * 64;    // global row b*N+i (64 | 512)
  const int d0 = blockIdx.y * 32;
  const int b = row0 >> 9;
  const int jbase = w * 128;  // wave-private j-range (4 K-steps of 32)
  const ushort* __restrict__ Bh = Mt_h + (size_t)b * D_ * N_;
  const ushort* __restrict__ Bl = Mt_l + (size_t)b * D_ * N_;
  size_t oA[4];
#pragma unroll
  for (int fi = 0; fi < 4; ++fi)
    oA[fi] = (size_t)(row0 + fi * 16 + r) * N_ + jbase + g * 8;
  const size_t oB = (size_t)(d0 + r) * N_ + jbase + g * 8;
  const size_t oB2 = oB + (size_t)16 * N_;
  f32x4 acc[4][2] = {};
  bf16x8 A[2][8], Bv[2][4];
#define K3LOAD(s, j0)                                                        \
  A[s][0] = ld8(ah + oA[0] + (j0)); A[s][1] = ld8(ah + oA[1] + (j0));        \
  A[s][2] = ld8(ah + oA[2] + (j0)); A[s][3] = ld8(ah + oA[3] + (j0));        \
  A[s][4] = ld8(al + oA[0] + (j0)); A[s][5] = ld8(al + oA[1] + (j0));        \
  A[s][6] = ld8(al + oA[2] + (j0)); A[s][7] = ld8(al + oA[3] + (j0));        \
  Bv[s][0] = ld8(Bh + oB + (j0));   Bv[s][1] = ld8(Bh + oB2 + (j0));         \
  Bv[s][2] = ld8(Bl + oB + (j0));   Bv[s][3] = ld8(Bl + oB2 + (j0));
#define K3MM(s)                                                              \
  _Pragma("unroll") for (int fi = 0; fi < 4; ++fi)                           \
  _Pragma("unroll") for (int fd = 0; fd < 2; ++fd) {                         \
    acc[fi][fd] = MFMA(A[s][fi], Bv[s][fd], acc[fi][fd]);                    \
    acc[fi][fd] = MFMA(A[s][fi], Bv[s][fd + 2], acc[fi][fd]);                \
    acc[fi][fd] = MFMA(A[s][fi + 4], Bv[s][fd], acc[fi][fd]);                \
  }
  K3LOAD(0, 0)
#pragma unroll
  for (int kt = 0; kt < 4; ++kt) {
    if (kt & 1) {
      if (kt < 3) { K3LOAD(0, (kt + 1) * 32) }
      K3MM(1)
    } else {
      if (kt < 3) { K3LOAD(1, (kt + 1) * 32) }
      K3MM(0)
    }
  }
#undef K3LOAD
#undef K3MM
#pragma unroll
  for (int fi = 0; fi < 4; ++fi)
#pragma unroll
    for (int fd = 0; fd < 2; ++fd)
#pragma unroll
      for (int rr = 0; rr < 4; ++rr)
        l_red[w][fi * 16 + g * 4 + rr][fd * 16 + r] = acc[fi][fd][rr];
  __syncthreads();
#pragma unroll
  for (int k = 0; k < 8; ++k) {
    const int row = (t >> 5) + k * 8;
    const int col = t & 31;
    const float v = l_red[0][row][col] + l_red[1][row][col] +
                    l_red[2][row][col] + l_red[3][row][col];
    out[(size_t)(row0 + row) * D_ + d0 + col] = v;
  }
}

extern "C" void kernel_launch(void* const* d_in, const int* in_sizes, int n_in,
                              void* d_out, int out_size, void* d_ws,
                              size_t ws_size, hipStream_t stream) {
  const float* M = (const float*)d_in[0];
  const int* mask = (const int*)d_in[1];
  const float* W1 = (const float*)d_in[2];
  const float* b1 = (const float*)d_in[3];
  const float* W2 = (const float*)d_in[4];
  const float* b2 = (const float*)d_in[5];
  const float* vw = (const float*)d_in[6];
  float* out = (float*)d_out;

  // workspace carve-up: ~18.75 MB total
  float* w1e = (float*)d_ws;                      // [2048][128] f32   1 MB
  float* w2e = w1e + 2048 * A_;                   // [4][128][512]     1 MB
  ushort* ah = (ushort*)(w2e + 4 * A_ * N_);      // [2048][512] bf16  2 MB
  ushort* al = ah + 2048 * N_;                    //                   2 MB
  ushort* Mr_h = al + 2048 * N_;                  // [2048][768] bf16  3 MB
  ushort* Mr_l = Mr_h + 2048 * D_;                //                   3 MB
  ushort* Mt_h = Mr_l + 2048 * D_;                // [4][768][512]     3 MB
  ushort* Mt_l = Mt_h + 2048 * D_;                //                   3 MB
  ushort* Wt_h = Mt_l + 2048 * D_;                // [256][768] bf16   .375
  ushort* Wt_l = Wt_h + 256 * D_;                 //                   .375
  float* uvec = (float*)(Wt_l + 256 * D_);        // [128] f32         512B

  k0_prep<<<864, 256, 0, stream>>>(M, W1, W2, vw, Mr_h, Mr_l, Mt_h, Mt_l,
                                   Wt_h, Wt_l, uvec);
  k1_mfma<<<dim3(2048 / 32, 8), 256, 0, stream>>>(Mr_h, Mr_l, Wt_h, Wt_l,
                                                  b1, b2, w1e, w2e);
  k2_scores<<<(B_ * N_) / 8, 512, 0, stream>>>(w1e, w2e, uvec, mask, vw,
                                               ah, al);
  k3_mfma<<<dim3(2048 / 64, D_ / 32), 256, 0, stream>>>(ah, al, Mt_h, Mt_l,
                                                        out);
}

// Round 13
// 80.042 us; speedup vs baseline: 6.1078x; 6.1078x over previous
//
#include <hip/hip_runtime.h>

#define B_ 4
#define N_ 512
#define D_ 768
#define A_ 128

typedef short bf16x8 __attribute__((ext_vector_type(8)));
typedef ushort u16x8 __attribute__((ext_vector_type(8)));
typedef float f32x4 __attribute__((ext_vector_type(4)));

__device__ __forceinline__ ushort f2h(float x) {  // f32 -> bf16 bits, RNE
  uint u = __builtin_bit_cast(uint, x);
  return (ushort)((u + 0x7fffu + ((u >> 16) & 1u)) >> 16);
}
__device__ __forceinline__ float h2f(ushort h) {
  uint u = ((uint)h) << 16;
  return __builtin_bit_cast(float, u);
}
__device__ __forceinline__ bf16x8 ld8(const ushort* p) {
  return *(const bf16x8*)p;
}
#define MFMA(a, b, c) __builtin_amdgcn_mfma_f32_16x16x32_bf16(a, b, c, 0, 0, 0)

// ---------------------------------------------------------------------------
// k0: fused prep (+ uvec = -2*v write). Unchanged from R11.
// ---------------------------------------------------------------------------
__global__ __launch_bounds__(256) void k0_prep(
    const float* __restrict__ M, const float* __restrict__ W1,
    const float* __restrict__ W2, const float* __restrict__ vw,
    ushort* __restrict__ Mr_h, ushort* __restrict__ Mr_l,
    ushort* __restrict__ Mt_h, ushort* __restrict__ Mt_l,
    ushort* __restrict__ Wt_h, ushort* __restrict__ Wt_l,
    float* __restrict__ uvec) {
  __shared__ ushort lds_h[64][40];
  __shared__ ushort lds_l[64][40];
  const int t = threadIdx.x;
  const int bid = blockIdx.x;
  if (bid < 768) {  // ---- M part ----
    const int dq = bid % 12;
    const int rest = bid / 12;
    const int d0 = dq * 64;
    const int n0 = (rest & 15) * 32;
    const int b = rest >> 4;
    const int n = t >> 3;          // 0..31
    const int dg = (t & 7) * 8;    // 0..56
    const size_t roff = ((size_t)(b * N_ + n0 + n)) * D_ + d0 + dg;
    const float4 v0 = *(const float4*)(M + roff);
    const float4 v1 = *(const float4*)(M + roff + 4);
    const float x[8] = {v0.x, v0.y, v0.z, v0.w, v1.x, v1.y, v1.z, v1.w};
    u16x8 vh, vl;
#pragma unroll
    for (int e = 0; e < 8; ++e) {
      ushort h = f2h(x[e]);
      ushort l = f2h(x[e] - h2f(h));
      vh[e] = h;
      vl[e] = l;
      lds_h[dg + e][n] = h;
      lds_l[dg + e][n] = l;
    }
    *(u16x8*)(Mr_h + roff) = vh;
    *(u16x8*)(Mr_l + roff) = vl;
    __syncthreads();
    const int dd = t >> 2;          // 0..63
    const int ng = (t & 3) * 8;     // 0..24
    const size_t toff = ((size_t)b * D_ + d0 + dd) * N_ + n0 + ng;
    *(u16x8*)(Mt_h + toff) = *(const u16x8*)(&lds_h[dd][ng]);
    *(u16x8*)(Mt_l + toff) = *(const u16x8*)(&lds_l[dd][ng]);
  } else {  // ---- W part ----
    const int c = t;
    const int k0 = (bid - 768) * 8;
    const float* __restrict__ Wp = (c < A_) ? W1 : W2;
    const int cc = c & (A_ - 1);
    u16x8 vh, vl;
#pragma unroll
    for (int e = 0; e < 8; ++e) {
      float x = Wp[(size_t)(k0 + e) * A_ + cc];
      ushort h = f2h(x);
      vh[e] = h;
      vl[e] = f2h(x - h2f(h));
    }
    *(u16x8*)(Wt_h + (size_t)c * D_ + k0) = vh;
    *(u16x8*)(Wt_l + (size_t)c * D_ + k0) = vl;
    if (bid == 768 && c < A_) uvec[c] = -2.f * vw[c];
  }
}

// ---------------------------------------------------------------------------
// k1 v3: M @ [W1|W2] -> EXPONENTIALS (unchanged from R11).
// ---------------------------------------------------------------------------
__global__ __launch_bounds__(256) void k1_mfma(
    const ushort* __restrict__ Mr_h, const ushort* __restrict__ Mr_l,
    const ushort* __restrict__ Wt_h, const ushort* __restrict__ Wt_l,
    const float* __restrict__ b1, const float* __restrict__ b2,
    float* __restrict__ w1e, float* __restrict__ w2e) {
  __shared__ float l_red[4][32][33];  // 16.9 KB
  const int t = threadIdx.x;
  const int l = t & 63;
  const int w = t >> 6;
  const int r = l & 15, g = l >> 4;
  const int row0 = blockIdx.x * 32;
  const int cb = blockIdx.y * 32;
  const int kbase = w * 192;  // wave-private K-range (6 K-steps of 32)
  const size_t oA = (size_t)(row0 + r) * D_ + kbase + g * 8;
  const size_t oA2 = oA + (size_t)16 * D_;
  const size_t oB = (size_t)(cb + r) * D_ + kbase + g * 8;
  const size_t oB2 = oB + (size_t)16 * D_;
  f32x4 acc[2][2] = {};
  bf16x8 A[2][4], Bv[2][4];
#define K1LOAD(s, k0)                                                        \
  A[s][0] = ld8(Mr_h + oA + (k0));  A[s][1] = ld8(Mr_h + oA2 + (k0));        \
  A[s][2] = ld8(Mr_l + oA + (k0));  A[s][3] = ld8(Mr_l + oA2 + (k0));        \
  Bv[s][0] = ld8(Wt_h + oB + (k0)); Bv[s][1] = ld8(Wt_h + oB2 + (k0));       \
  Bv[s][2] = ld8(Wt_l + oB + (k0)); Bv[s][3] = ld8(Wt_l + oB2 + (k0));
#define K1MM(s)                                                              \
  acc[0][0] = MFMA(A[s][0], Bv[s][0], acc[0][0]);                            \
  acc[0][0] = MFMA(A[s][0], Bv[s][2], acc[0][0]);                            \
  acc[0][0] = MFMA(A[s][2], Bv[s][0], acc[0][0]);                            \
  acc[0][1] = MFMA(A[s][0], Bv[s][1], acc[0][1]);                            \
  acc[0][1] = MFMA(A[s][0], Bv[s][3], acc[0][1]);                            \
  acc[0][1] = MFMA(A[s][2], Bv[s][1], acc[0][1]);                            \
  acc[1][0] = MFMA(A[s][1], Bv[s][0], acc[1][0]);                            \
  acc[1][0] = MFMA(A[s][1], Bv[s][2], acc[1][0]);                            \
  acc[1][0] = MFMA(A[s][3], Bv[s][0], acc[1][0]);                            \
  acc[1][1] = MFMA(A[s][1], Bv[s][1], acc[1][1]);                            \
  acc[1][1] = MFMA(A[s][1], Bv[s][3], acc[1][1]);                            \
  acc[1][1] = MFMA(A[s][3], Bv[s][1], acc[1][1]);
  K1LOAD(0, 0)
#pragma unroll
  for (int kt = 0; kt < 6; ++kt) {
    if (kt & 1) {
      if (kt < 5) { K1LOAD(0, (kt + 1) * 32) }
      K1MM(1)
    } else {
      if (kt < 5) { K1LOAD(1, (kt + 1) * 32) }
      K1MM(0)
    }
  }
#undef K1LOAD
#undef K1MM
#pragma unroll
  for (int fi = 0; fi < 2; ++fi)
#pragma unroll
    for (int fj = 0; fj < 2; ++fj)
#pragma unroll
      for (int rr = 0; rr < 4; ++rr)
        l_red[w][fi * 16 + g * 4 + rr][fj * 16 + r] = acc[fi][fj][rr];
  __syncthreads();

  const float SC = 2.8853900817779268f;  // 2*log2(e): e^{2x} = 2^{SC*x}
  const int b = row0 >> 9;
  const int n0 = row0 & (N_ - 1);
  if (cb < A_) {  // E1: w1e[row][col], col-fast coalesced
#pragma unroll
    for (int k = 0; k < 4; ++k) {
      const int row = (t >> 5) + k * 8;
      const int col = t & 31;
      float v = l_red[0][row][col] + l_red[1][row][col] +
                l_red[2][row][col] + l_red[3][row][col];
      v = (v + b1[cb + col]) * SC;
      w1e[(size_t)(row0 + row) * A_ + cb + col] = __builtin_amdgcn_exp2f(v);
    }
  } else {  // E2: w2e[(b*128 + a)*512 + n], row(n)-fast coalesced
#pragma unroll
    for (int k = 0; k < 4; ++k) {
      const int row = t & 31;
      const int col = (t >> 5) + k * 8;
      float v = l_red[0][row][col] + l_red[1][row][col] +
                l_red[2][row][col] + l_red[3][row][col];
      v = (v + b2[cb - A_ + col]) * SC;
      w2e[(size_t)(b * A_ + cb - A_ + col) * N_ + n0 + row] =
          __builtin_amdgcn_exp2f(v);
    }
  }
}

// ---------------------------------------------------------------------------
// k2 v13: v12's loop interchange (a-chunk outer, 8x fewer E1/u broadcast
// loads) with CONTROLLED REGISTER PRESSURE (v12 spilled: VGPR 128 cap,
// 580MB scratch writes). Changes vs v12:
//  - unroll 1 on cc and aa loops (only jt x8 inner unrolled)
//  - wa/uu loaded per-aa (no waq/uuq arrays)
//  - mask loads deferred to after the main loop
// Live set ~ s[8]+st[16]+wa/uu[8]+addr => no spill.
// ---------------------------------------------------------------------------
__global__ __launch_bounds__(512) void k2_scores(
    const float* __restrict__ w1e, const float* __restrict__ w2e,
    const float* __restrict__ uvec, const int* __restrict__ mask,
    const float* __restrict__ vw, ushort* __restrict__ ah,
    ushort* __restrict__ al) {
  __shared__ float l_w2[2][16][N_];  // 64 KB: [buf][a_local][j]
  const int t = threadIdx.x;
  const int lane = t & 63;
  const int w = t >> 6;
  const int i0 = blockIdx.x * 8;
  const int b = i0 >> 9;
  const int i = i0 + w;
  const float* __restrict__ w1row = w1e + (size_t)i * A_;  // uniform addr/wave

  float vs = vw[lane] + vw[64 + lane];  // Vsum via butterfly
#pragma unroll
  for (int off = 32; off; off >>= 1) vs += __shfl_xor(vs, off);

  const float* __restrict__ w2src = w2e + (size_t)b * A_ * N_;
  float4 st[4];  // staging: tile = 16 a x 512 j = 2048 f4 / 512 thr

#define STAGE_LOAD(cc)                                                      \
  {                                                                         \
    const float* __restrict__ src = w2src + (size_t)(cc) * 16 * N_;         \
    _Pragma("unroll") for (int k = 0; k < 4; ++k) {                         \
      const int f = t + k * 512;                                            \
      st[k] = *(const float4*)(src + (size_t)(f >> 7) * N_ + (f & 127) * 4);\
    }                                                                       \
  }
#define STAGE_WRITE(bf)                                                     \
  {                                                                         \
    _Pragma("unroll") for (int k = 0; k < 4; ++k) {                         \
      const int f = t + k * 512;                                            \
      *(float4*)(&l_w2[bf][f >> 7][(f & 127) * 4]) = st[k];                 \
    }                                                                       \
  }

  STAGE_LOAD(0)
  STAGE_WRITE(0)
  __syncthreads();

  float s[8] = {};
#pragma unroll 1
  for (int cc = 0; cc < 8; ++cc) {
    if (cc + 1 < 8) STAGE_LOAD(cc + 1)  // issue early (T14)
    const float(*wb)[N_] = l_w2[cc & 1];
#pragma unroll 1
    for (int aa = 0; aa < 4; ++aa) {
      const float4 wa = *(const float4*)(w1row + cc * 16 + aa * 4);
      const float4 uu = *(const float4*)(uvec + cc * 16 + aa * 4);
#pragma unroll
      for (int jt = 0; jt < 8; ++jt) {
        const int jj = jt * 64 + lane;
        const float x0 = wb[aa * 4 + 0][jj];
        const float x1 = wb[aa * 4 + 1][jj];
        const float x2 = wb[aa * 4 + 2][jj];
        const float x3 = wb[aa * 4 + 3][jj];
        float acc = s[jt];
        acc = fmaf(uu.x, __builtin_amdgcn_rcpf(fmaf(wa.x, x0, 1.f)), acc);
        acc = fmaf(uu.y, __builtin_amdgcn_rcpf(fmaf(wa.y, x1, 1.f)), acc);
        acc = fmaf(uu.z, __builtin_amdgcn_rcpf(fmaf(wa.z, x2, 1.f)), acc);
        acc = fmaf(uu.w, __builtin_amdgcn_rcpf(fmaf(wa.w, x3, 1.f)), acc);
        s[jt] = acc;
      }
    }
    if (cc + 1 < 8) { STAGE_WRITE((cc + 1) & 1) }  // write late (T14)
    __syncthreads();
  }
#undef STAGE_LOAD
#undef STAGE_WRITE

  // masks loaded HERE (not live through the main loop)
  const float NEG = -3.402823466e38f;  // np.finfo(f32).min
#pragma unroll
  for (int jt = 0; jt < 8; ++jt) {
    const int mk = mask[(size_t)i * N_ + jt * 64 + lane];
    s[jt] = mk ? (vs + s[jt]) : NEG;
  }

  // fused softmax: 8 regs x 64 lanes = full row per wave
  float rmax = s[0];
#pragma unroll
  for (int jt = 1; jt < 8; ++jt) rmax = fmaxf(rmax, s[jt]);
#pragma unroll
  for (int off = 32; off; off >>= 1) rmax = fmaxf(rmax, __shfl_xor(rmax, off));
  const float L2E = 1.4426950408889634f;
  float psum = 0.f;
#pragma unroll
  for (int jt = 0; jt < 8; ++jt) {
    // all-masked row: s-rmax = 0 -> 1 -> uniform 1/512 (ref match);
    // masked in live row: (NEG-rmax)*L2E -> -inf -> exp2 = 0 exactly.
    s[jt] = __builtin_amdgcn_exp2f((s[jt] - rmax) * L2E);
    psum += s[jt];
  }
#pragma unroll
  for (int off = 32; off; off >>= 1) psum += __shfl_xor(psum, off);
  const float inv = __builtin_amdgcn_rcpf(psum);
#pragma unroll
  for (int jt = 0; jt < 8; ++jt) {
    const float pv = s[jt] * inv;
    const ushort hh = f2h(pv);
    ah[(size_t)i * N_ + jt * 64 + lane] = hh;
    al[(size_t)i * N_ + jt * 64 + lane] = f2h(pv - h2f(hh));
  }
}

// ---------------------------------------------------------------------------
// k3 v4: out[b] = attn[b] @ M[b] (unchanged from R11).
// ---------------------------------------------------------------------------
__global__ __launch_bounds__(256) void k3_mfma(
    const ushort* __restrict__ ah, const ushort* __restrict__ al,
    const ushort* __restrict__ Mt_h, const ushort* __restrict__ Mt_l,
    float* __restrict__ out) {
  __shared__ float l_red[4][64][33];  // 33.8 KB
  const int t = threadIdx.x;
  const int l = t & 63;
  const int w = t >> 6;
  const int r = l & 15, g = l >> 4;
  const int row0 = blockIdx.x * 64;    // global row b*N+i (64 | 512)
  const int d0 = blockIdx.y * 32;
  const int b = row0 >> 9;
  const int jbase = w * 128;  // wave-private j-range (4 K-steps of 32)
  const ushort* __restrict__ Bh = Mt_h + (size_t)b * D_ * N_;
  const ushort* __restrict__ Bl = Mt_l + (size_t)b * D_ * N_;
  size_t oA[4];
#pragma unroll
  for (int fi = 0; fi < 4; ++fi)
    oA[fi] = (size_t)(row0 + fi * 16 + r) * N_ + jbase + g * 8;
  const size_t oB = (size_t)(d0 + r) * N_ + jbase + g * 8;
  const size_t oB2 = oB + (size_t)16 * N_;
  f32x4 acc[4][2] = {};
  bf16x8 A[2][8], Bv[2][4];
#define K3LOAD(s, j0)                                                        \
  A[s][0] = ld8(ah + oA[0] + (j0)); A[s][1] = ld8(ah + oA[1] + (j0));        \
  A[s][2] = ld8(ah + oA[2] + (j0)); A[s][3] = ld8(ah + oA[3] + (j0));        \
  A[s][4] = ld8(al + oA[0] + (j0)); A[s][5] = ld8(al + oA[1] + (j0));        \
  A[s][6] = ld8(al + oA[2] + (j0)); A[s][7] = ld8(al + oA[3] + (j0));        \
  Bv[s][0] = ld8(Bh + oB + (j0));   Bv[s][1] = ld8(Bh + oB2 + (j0));         \
  Bv[s][2] = ld8(Bl + oB + (j0));   Bv[s][3] = ld8(Bl + oB2 + (j0));
#define K3MM(s)                                                              \
  _Pragma("unroll") for (int fi = 0; fi < 4; ++fi)                           \
  _Pragma("unroll") for (int fd = 0; fd < 2; ++fd) {                         \
    acc[fi][fd] = MFMA(A[s][fi], Bv[s][fd], acc[fi][fd]);                    \
    acc[fi][fd] = MFMA(A[s][fi], Bv[s][fd + 2], acc[fi][fd]);                \
    acc[fi][fd] = MFMA(A[s][fi + 4], Bv[s][fd], acc[fi][fd]);                \
  }
  K3LOAD(0, 0)
#pragma unroll
  for (int kt = 0; kt < 4; ++kt) {
    if (kt & 1) {
      if (kt < 3) { K3LOAD(0, (kt + 1) * 32) }
      K3MM(1)
    } else {
      if (kt < 3) { K3LOAD(1, (kt + 1) * 32) }
      K3MM(0)
    }
  }
#undef K3LOAD
#undef K3MM
#pragma unroll
  for (int fi = 0; fi < 4; ++fi)
#pragma unroll
    for (int fd = 0; fd < 2; ++fd)
#pragma unroll
      for (int rr = 0; rr < 4; ++rr)
        l_red[w][fi * 16 + g * 4 + rr][fd * 16 + r] = acc[fi][fd][rr];
  __syncthreads();
#pragma unroll
  for (int k = 0; k < 8; ++k) {
    const int row = (t >> 5) + k * 8;
    const int col = t & 31;
    const float v = l_red[0][row][col] + l_red[1][row][col] +
                    l_red[2][row][col] + l_red[3][row][col];
    out[(size_t)(row0 + row) * D_ + d0 + col] = v;
  }
}

extern "C" void kernel_launch(void* const* d_in, const int* in_sizes, int n_in,
                              void* d_out, int out_size, void* d_ws,
                              size_t ws_size, hipStream_t stream) {
  const float* M = (const float*)d_in[0];
  const int* mask = (const int*)d_in[1];
  const float* W1 = (const float*)d_in[2];
  const float* b1 = (const float*)d_in[3];
  const float* W2 = (const float*)d_in[4];
  const float* b2 = (const float*)d_in[5];
  const float* vw = (const float*)d_in[6];
  float* out = (float*)d_out;

  // workspace carve-up: ~18.75 MB total
  float* w1e = (float*)d_ws;                      // [2048][128] f32   1 MB
  float* w2e = w1e + 2048 * A_;                   // [4][128][512]     1 MB
  ushort* ah = (ushort*)(w2e + 4 * A_ * N_);      // [2048][512] bf16  2 MB
  ushort* al = ah + 2048 * N_;                    //                   2 MB
  ushort* Mr_h = al + 2048 * N_;                  // [2048][768] bf16  3 MB
  ushort* Mr_l = Mr_h + 2048 * D_;                //                   3 MB
  ushort* Mt_h = Mr_l + 2048 * D_;                // [4][768][512]     3 MB
  ushort* Mt_l = Mt_h + 2048 * D_;                //                   3 MB
  ushort* Wt_h = Mt_l + 2048 * D_;                // [256][768] bf16   .375
  ushort* Wt_l = Wt_h + 256 * D_;                 //                   .375
  float* uvec = (float*)(Wt_l + 256 * D_);        // [128] f32         512B

  k0_prep<<<864, 256, 0, stream>>>(M, W1, W2, vw, Mr_h, Mr_l, Mt_h, Mt_l,
                                   Wt_h, Wt_l, uvec);
  k1_mfma<<<dim3(2048 / 32, 8), 256, 0, stream>>>(Mr_h, Mr_l, Wt_h, Wt_l,
                                                  b1, b2, w1e, w2e);
  k2_scores<<<(B_ * N_) / 8, 512, 0, stream>>>(w1e, w2e, uvec, mask, vw,
                                               ah, al);
  k3_mfma<<<dim3(2048 / 64, D_ / 32), 256, 0, stream>>>(ah, al, Mt_h, Mt_l,
                                                        out);
}

// Round 14
// 79.826 us; speedup vs baseline: 6.1243x; 1.0027x over previous
//
#include <hip/hip_runtime.h>

#define B_ 4
#define N_ 512
#define D_ 768
#define A_ 128

typedef short bf16x8 __attribute__((ext_vector_type(8)));
typedef ushort u16x8 __attribute__((ext_vector_type(8)));
typedef ushort u16x4 __attribute__((ext_vector_type(4)));
typedef float f32x4 __attribute__((ext_vector_type(4)));

__device__ __forceinline__ ushort f2h(float x) {  // f32 -> bf16 bits, RNE
  uint u = __builtin_bit_cast(uint, x);
  return (ushort)((u + 0x7fffu + ((u >> 16) & 1u)) >> 16);
}
__device__ __forceinline__ float h2f(ushort h) {
  uint u = ((uint)h) << 16;
  return __builtin_bit_cast(float, u);
}
__device__ __forceinline__ bf16x8 ld8(const ushort* p) {
  return *(const bf16x8*)p;
}
#define MFMA(a, b, c) __builtin_amdgcn_mfma_f32_16x16x32_bf16(a, b, c, 0, 0, 0)

// ---------------------------------------------------------------------------
// k0: fused prep (+ uvec = -2*v write). Unchanged from R13.
// ---------------------------------------------------------------------------
__global__ __launch_bounds__(256) void k0_prep(
    const float* __restrict__ M, const float* __restrict__ W1,
    const float* __restrict__ W2, const float* __restrict__ vw,
    ushort* __restrict__ Mr_h, ushort* __restrict__ Mr_l,
    ushort* __restrict__ Mt_h, ushort* __restrict__ Mt_l,
    ushort* __restrict__ Wt_h, ushort* __restrict__ Wt_l,
    float* __restrict__ uvec) {
  __shared__ ushort lds_h[64][40];
  __shared__ ushort lds_l[64][40];
  const int t = threadIdx.x;
  const int bid = blockIdx.x;
  if (bid < 768) {  // ---- M part ----
    const int dq = bid % 12;
    const int rest = bid / 12;
    const int d0 = dq * 64;
    const int n0 = (rest & 15) * 32;
    const int b = rest >> 4;
    const int n = t >> 3;          // 0..31
    const int dg = (t & 7) * 8;    // 0..56
    const size_t roff = ((size_t)(b * N_ + n0 + n)) * D_ + d0 + dg;
    const float4 v0 = *(const float4*)(M + roff);
    const float4 v1 = *(const float4*)(M + roff + 4);
    const float x[8] = {v0.x, v0.y, v0.z, v0.w, v1.x, v1.y, v1.z, v1.w};
    u16x8 vh, vl;
#pragma unroll
    for (int e = 0; e < 8; ++e) {
      ushort h = f2h(x[e]);
      ushort l = f2h(x[e] - h2f(h));
      vh[e] = h;
      vl[e] = l;
      lds_h[dg + e][n] = h;
      lds_l[dg + e][n] = l;
    }
    *(u16x8*)(Mr_h + roff) = vh;
    *(u16x8*)(Mr_l + roff) = vl;
    __syncthreads();
    const int dd = t >> 2;          // 0..63
    const int ng = (t & 3) * 8;     // 0..24
    const size_t toff = ((size_t)b * D_ + d0 + dd) * N_ + n0 + ng;
    *(u16x8*)(Mt_h + toff) = *(const u16x8*)(&lds_h[dd][ng]);
    *(u16x8*)(Mt_l + toff) = *(const u16x8*)(&lds_l[dd][ng]);
  } else {  // ---- W part ----
    const int c = t;
    const int k0 = (bid - 768) * 8;
    const float* __restrict__ Wp = (c < A_) ? W1 : W2;
    const int cc = c & (A_ - 1);
    u16x8 vh, vl;
#pragma unroll
    for (int e = 0; e < 8; ++e) {
      float x = Wp[(size_t)(k0 + e) * A_ + cc];
      ushort h = f2h(x);
      vh[e] = h;
      vl[e] = f2h(x - h2f(h));
    }
    *(u16x8*)(Wt_h + (size_t)c * D_ + k0) = vh;
    *(u16x8*)(Wt_l + (size_t)c * D_ + k0) = vl;
    if (bid == 768 && c < A_) uvec[c] = -2.f * vw[c];
  }
}

// ---------------------------------------------------------------------------
// k1 v3: M @ [W1|W2] -> EXPONENTIALS (unchanged from R13).
// ---------------------------------------------------------------------------
__global__ __launch_bounds__(256) void k1_mfma(
    const ushort* __restrict__ Mr_h, const ushort* __restrict__ Mr_l,
    const ushort* __restrict__ Wt_h, const ushort* __restrict__ Wt_l,
    const float* __restrict__ b1, const float* __restrict__ b2,
    float* __restrict__ w1e, float* __restrict__ w2e) {
  __shared__ float l_red[4][32][33];  // 16.9 KB
  const int t = threadIdx.x;
  const int l = t & 63;
  const int w = t >> 6;
  const int r = l & 15, g = l >> 4;
  const int row0 = blockIdx.x * 32;
  const int cb = blockIdx.y * 32;
  const int kbase = w * 192;  // wave-private K-range (6 K-steps of 32)
  const size_t oA = (size_t)(row0 + r) * D_ + kbase + g * 8;
  const size_t oA2 = oA + (size_t)16 * D_;
  const size_t oB = (size_t)(cb + r) * D_ + kbase + g * 8;
  const size_t oB2 = oB + (size_t)16 * D_;
  f32x4 acc[2][2] = {};
  bf16x8 A[2][4], Bv[2][4];
#define K1LOAD(s, k0)                                                        \
  A[s][0] = ld8(Mr_h + oA + (k0));  A[s][1] = ld8(Mr_h + oA2 + (k0));        \
  A[s][2] = ld8(Mr_l + oA + (k0));  A[s][3] = ld8(Mr_l + oA2 + (k0));        \
  Bv[s][0] = ld8(Wt_h + oB + (k0)); Bv[s][1] = ld8(Wt_h + oB2 + (k0));       \
  Bv[s][2] = ld8(Wt_l + oB + (k0)); Bv[s][3] = ld8(Wt_l + oB2 + (k0));
#define K1MM(s)                                                              \
  acc[0][0] = MFMA(A[s][0], Bv[s][0], acc[0][0]);                            \
  acc[0][0] = MFMA(A[s][0], Bv[s][2], acc[0][0]);                            \
  acc[0][0] = MFMA(A[s][2], Bv[s][0], acc[0][0]);                            \
  acc[0][1] = MFMA(A[s][0], Bv[s][1], acc[0][1]);                            \
  acc[0][1] = MFMA(A[s][0], Bv[s][3], acc[0][1]);                            \
  acc[0][1] = MFMA(A[s][2], Bv[s][1], acc[0][1]);                            \
  acc[1][0] = MFMA(A[s][1], Bv[s][0], acc[1][0]);                            \
  acc[1][0] = MFMA(A[s][1], Bv[s][2], acc[1][0]);                            \
  acc[1][0] = MFMA(A[s][3], Bv[s][0], acc[1][0]);                            \
  acc[1][1] = MFMA(A[s][1], Bv[s][1], acc[1][1]);                            \
  acc[1][1] = MFMA(A[s][1], Bv[s][3], acc[1][1]);                            \
  acc[1][1] = MFMA(A[s][3], Bv[s][1], acc[1][1]);
  K1LOAD(0, 0)
#pragma unroll
  for (int kt = 0; kt < 6; ++kt) {
    if (kt & 1) {
      if (kt < 5) { K1LOAD(0, (kt + 1) * 32) }
      K1MM(1)
    } else {
      if (kt < 5) { K1LOAD(1, (kt + 1) * 32) }
      K1MM(0)
    }
  }
#undef K1LOAD
#undef K1MM
#pragma unroll
  for (int fi = 0; fi < 2; ++fi)
#pragma unroll
    for (int fj = 0; fj < 2; ++fj)
#pragma unroll
      for (int rr = 0; rr < 4; ++rr)
        l_red[w][fi * 16 + g * 4 + rr][fj * 16 + r] = acc[fi][fj][rr];
  __syncthreads();

  const float SC = 2.8853900817779268f;  // 2*log2(e): e^{2x} = 2^{SC*x}
  const int b = row0 >> 9;
  const int n0 = row0 & (N_ - 1);
  if (cb < A_) {  // E1: w1e[row][col], col-fast coalesced
#pragma unroll
    for (int k = 0; k < 4; ++k) {
      const int row = (t >> 5) + k * 8;
      const int col = t & 31;
      float v = l_red[0][row][col] + l_red[1][row][col] +
                l_red[2][row][col] + l_red[3][row][col];
      v = (v + b1[cb + col]) * SC;
      w1e[(size_t)(row0 + row) * A_ + cb + col] = __builtin_amdgcn_exp2f(v);
    }
  } else {  // E2: w2e[(b*128 + a)*512 + n], row(n)-fast coalesced
#pragma unroll
    for (int k = 0; k < 4; ++k) {
      const int row = t & 31;
      const int col = (t >> 5) + k * 8;
      float v = l_red[0][row][col] + l_red[1][row][col] +
                l_red[2][row][col] + l_red[3][row][col];
      v = (v + b2[cb - A_ + col]) * SC;
      w2e[(size_t)(b * A_ + cb - A_ + col) * N_ + n0 + row] =
          __builtin_amdgcn_exp2f(v);
    }
  }
}

// ---------------------------------------------------------------------------
// k2 v14: b128 LDS reads — lane owns 4 CONSECUTIVE j (j = jt*256+lane*4+e,
// jt=0,1). Per a: ONE ds_read_b128 serves 4 elements (4x fewer LDS instrs,
// 2x bytes/cyc: LDS floor 47.5K -> ~25K cyc/CU). Masks = 2 int4 loads;
// output = ushort4 stores; accumulators float4 s0,s1 (static idx).
// Structure (a-chunk outer, T14 staging, unroll 1 on cc/aa) as v13.
// ---------------------------------------------------------------------------
__global__ __launch_bounds__(512) void k2_scores(
    const float* __restrict__ w1e, const float* __restrict__ w2e,
    const float* __restrict__ uvec, const int* __restrict__ mask,
    const float* __restrict__ vw, ushort* __restrict__ ah,
    ushort* __restrict__ al) {
  __shared__ float l_w2[2][16][N_];  // 64 KB: [buf][a_local][j]
  const int t = threadIdx.x;
  const int lane = t & 63;
  const int w = t >> 6;
  const int i0 = blockIdx.x * 8;
  const int b = i0 >> 9;
  const int i = i0 + w;
  const float* __restrict__ w1row = w1e + (size_t)i * A_;  // uniform addr/wave

  float vs = vw[lane] + vw[64 + lane];  // Vsum via butterfly
#pragma unroll
  for (int off = 32; off; off >>= 1) vs += __shfl_xor(vs, off);

  const float* __restrict__ w2src = w2e + (size_t)b * A_ * N_;
  float4 st[4];  // staging: tile = 16 a x 512 j = 2048 f4 / 512 thr

#define STAGE_LOAD(cc)                                                      \
  {                                                                         \
    const float* __restrict__ src = w2src + (size_t)(cc) * 16 * N_;         \
    _Pragma("unroll") for (int k = 0; k < 4; ++k) {                         \
      const int f = t + k * 512;                                            \
      st[k] = *(const float4*)(src + (size_t)(f >> 7) * N_ + (f & 127) * 4);\
    }                                                                       \
  }
#define STAGE_WRITE(bf)                                                     \
  {                                                                         \
    _Pragma("unroll") for (int k = 0; k < 4; ++k) {                         \
      const int f = t + k * 512;                                            \
      *(float4*)(&l_w2[bf][f >> 7][(f & 127) * 4]) = st[k];                 \
    }                                                                       \
  }

  STAGE_LOAD(0)
  STAGE_WRITE(0)
  __syncthreads();

  float4 s0 = {0.f, 0.f, 0.f, 0.f};  // j = lane*4 + e        (jt 0)
  float4 s1 = {0.f, 0.f, 0.f, 0.f};  // j = 256 + lane*4 + e  (jt 1)
#pragma unroll 1
  for (int cc = 0; cc < 8; ++cc) {
    if (cc + 1 < 8) STAGE_LOAD(cc + 1)  // issue early (T14)
    const float(*wb)[N_] = l_w2[cc & 1];
#pragma unroll 1
    for (int aa = 0; aa < 4; ++aa) {
      const float4 wa = *(const float4*)(w1row + cc * 16 + aa * 4);
      const float4 uu = *(const float4*)(uvec + cc * 16 + aa * 4);
      const float wa_[4] = {wa.x, wa.y, wa.z, wa.w};
      const float uu_[4] = {uu.x, uu.y, uu.z, uu.w};
#pragma unroll
      for (int e = 0; e < 4; ++e) {
        const int a = aa * 4 + e;
        const float wx = wa_[e];
        const float ux = uu_[e];
        const float4 x0 = *(const float4*)(&wb[a][lane * 4]);
        const float4 x1 = *(const float4*)(&wb[a][256 + lane * 4]);
        s0.x = fmaf(ux, __builtin_amdgcn_rcpf(fmaf(wx, x0.x, 1.f)), s0.x);
        s0.y = fmaf(ux, __builtin_amdgcn_rcpf(fmaf(wx, x0.y, 1.f)), s0.y);
        s0.z = fmaf(ux, __builtin_amdgcn_rcpf(fmaf(wx, x0.z, 1.f)), s0.z);
        s0.w = fmaf(ux, __builtin_amdgcn_rcpf(fmaf(wx, x0.w, 1.f)), s0.w);
        s1.x = fmaf(ux, __builtin_amdgcn_rcpf(fmaf(wx, x1.x, 1.f)), s1.x);
        s1.y = fmaf(ux, __builtin_amdgcn_rcpf(fmaf(wx, x1.y, 1.f)), s1.y);
        s1.z = fmaf(ux, __builtin_amdgcn_rcpf(fmaf(wx, x1.z, 1.f)), s1.z);
        s1.w = fmaf(ux, __builtin_amdgcn_rcpf(fmaf(wx, x1.w, 1.f)), s1.w);
      }
    }
    if (cc + 1 < 8) { STAGE_WRITE((cc + 1) & 1) }  // write late (T14)
    __syncthreads();
  }
#undef STAGE_LOAD
#undef STAGE_WRITE

  // masks (coalesced int4), then scores
  const float NEG = -3.402823466e38f;  // np.finfo(f32).min
  const int4 mk0 = *(const int4*)(mask + (size_t)i * N_ + lane * 4);
  const int4 mk1 = *(const int4*)(mask + (size_t)i * N_ + 256 + lane * 4);
  s0.x = mk0.x ? (vs + s0.x) : NEG;
  s0.y = mk0.y ? (vs + s0.y) : NEG;
  s0.z = mk0.z ? (vs + s0.z) : NEG;
  s0.w = mk0.w ? (vs + s0.w) : NEG;
  s1.x = mk1.x ? (vs + s1.x) : NEG;
  s1.y = mk1.y ? (vs + s1.y) : NEG;
  s1.z = mk1.z ? (vs + s1.z) : NEG;
  s1.w = mk1.w ? (vs + s1.w) : NEG;

  // fused softmax: 8 values x 64 lanes = full row per wave
  float rmax = fmaxf(fmaxf(fmaxf(s0.x, s0.y), fmaxf(s0.z, s0.w)),
                     fmaxf(fmaxf(s1.x, s1.y), fmaxf(s1.z, s1.w)));
#pragma unroll
  for (int off = 32; off; off >>= 1) rmax = fmaxf(rmax, __shfl_xor(rmax, off));
  const float L2E = 1.4426950408889634f;
  // all-masked row: s-rmax = 0 -> 1 -> uniform 1/512 (ref match);
  // masked in live row: (NEG-rmax)*L2E -> -inf -> exp2 = 0 exactly.
  s0.x = __builtin_amdgcn_exp2f((s0.x - rmax) * L2E);
  s0.y = __builtin_amdgcn_exp2f((s0.y - rmax) * L2E);
  s0.z = __builtin_amdgcn_exp2f((s0.z - rmax) * L2E);
  s0.w = __builtin_amdgcn_exp2f((s0.w - rmax) * L2E);
  s1.x = __builtin_amdgcn_exp2f((s1.x - rmax) * L2E);
  s1.y = __builtin_amdgcn_exp2f((s1.y - rmax) * L2E);
  s1.z = __builtin_amdgcn_exp2f((s1.z - rmax) * L2E);
  s1.w = __builtin_amdgcn_exp2f((s1.w - rmax) * L2E);
  float psum = ((s0.x + s0.y) + (s0.z + s0.w)) +
               ((s1.x + s1.y) + (s1.z + s1.w));
#pragma unroll
  for (int off = 32; off; off >>= 1) psum += __shfl_xor(psum, off);
  const float inv = __builtin_amdgcn_rcpf(psum);

  const float p0[4] = {s0.x * inv, s0.y * inv, s0.z * inv, s0.w * inv};
  const float p1[4] = {s1.x * inv, s1.y * inv, s1.z * inv, s1.w * inv};
  u16x4 vh0, vl0, vh1, vl1;
#pragma unroll
  for (int e = 0; e < 4; ++e) {
    ushort hh = f2h(p0[e]);
    vh0[e] = hh;
    vl0[e] = f2h(p0[e] - h2f(hh));
    hh = f2h(p1[e]);
    vh1[e] = hh;
    vl1[e] = f2h(p1[e] - h2f(hh));
  }
  *(u16x4*)(ah + (size_t)i * N_ + lane * 4) = vh0;
  *(u16x4*)(al + (size_t)i * N_ + lane * 4) = vl0;
  *(u16x4*)(ah + (size_t)i * N_ + 256 + lane * 4) = vh1;
  *(u16x4*)(al + (size_t)i * N_ + 256 + lane * 4) = vl1;
}

// ---------------------------------------------------------------------------
// k3 v4: out[b] = attn[b] @ M[b] (unchanged from R13).
// ---------------------------------------------------------------------------
__global__ __launch_bounds__(256) void k3_mfma(
    const ushort* __restrict__ ah, const ushort* __restrict__ al,
    const ushort* __restrict__ Mt_h, const ushort* __restrict__ Mt_l,
    float* __restrict__ out) {
  __shared__ float l_red[4][64][33];  // 33.8 KB
  const int t = threadIdx.x;
  const int l = t & 63;
  const int w = t >> 6;
  const int r = l & 15, g = l >> 4;
  const int row0 = blockIdx.x * 64;    // global row b*N+i (64 | 512)
  const int d0 = blockIdx.y * 32;
  const int b = row0 >> 9;
  const int jbase = w * 128;  // wave-private j-range (4 K-steps of 32)
  const ushort* __restrict__ Bh = Mt_h + (size_t)b * D_ * N_;
  const ushort* __restrict__ Bl = Mt_l + (size_t)b * D_ * N_;
  size_t oA[4];
#pragma unroll
  for (int fi = 0; fi < 4; ++fi)
    oA[fi] = (size_t)(row0 + fi * 16 + r) * N_ + jbase + g * 8;
  const size_t oB = (size_t)(d0 + r) * N_ + jbase + g * 8;
  const size_t oB2 = oB + (size_t)16 * N_;
  f32x4 acc[4][2] = {};
  bf16x8 A[2][8], Bv[2][4];
#define K3LOAD(s, j0)                                                        \
  A[s][0] = ld8(ah + oA[0] + (j0)); A[s][1] = ld8(ah + oA[1] + (j0));        \
  A[s][2] = ld8(ah + oA[2] + (j0)); A[s][3] = ld8(ah + oA[3] + (j0));        \
  A[s][4] = ld8(al + oA[0] + (j0)); A[s][5] = ld8(al + oA[1] + (j0));        \
  A[s][6] = ld8(al + oA[2] + (j0)); A[s][7] = ld8(al + oA[3] + (j0));        \
  Bv[s][0] = ld8(Bh + oB + (j0));   Bv[s][1] = ld8(Bh + oB2 + (j0));         \
  Bv[s][2] = ld8(Bl + oB + (j0));   Bv[s][3] = ld8(Bl + oB2 + (j0));
#define K3MM(s)                                                              \
  _Pragma("unroll") for (int fi = 0; fi < 4; ++fi)                           \
  _Pragma("unroll") for (int fd = 0; fd < 2; ++fd) {                         \
    acc[fi][fd] = MFMA(A[s][fi], Bv[s][fd], acc[fi][fd]);                    \
    acc[fi][fd] = MFMA(A[s][fi], Bv[s][fd + 2], acc[fi][fd]);                \
    acc[fi][fd] = MFMA(A[s][fi + 4], Bv[s][fd], acc[fi][fd]);                \
  }
  K3LOAD(0, 0)
#pragma unroll
  for (int kt = 0; kt < 4; ++kt) {
    if (kt & 1) {
      if (kt < 3) { K3LOAD(0, (kt + 1) * 32) }
      K3MM(1)
    } else {
      if (kt < 3) { K3LOAD(1, (kt + 1) * 32) }
      K3MM(0)
    }
  }
#undef K3LOAD
#undef K3MM
#pragma unroll
  for (int fi = 0; fi < 4; ++fi)
#pragma unroll
    for (int fd = 0; fd < 2; ++fd)
#pragma unroll
      for (int rr = 0; rr < 4; ++rr)
        l_red[w][fi * 16 + g * 4 + rr][fd * 16 + r] = acc[fi][fd][rr];
  __syncthreads();
#pragma unroll
  for (int k = 0; k < 8; ++k) {
    const int row = (t >> 5) + k * 8;
    const int col = t & 31;
    const float v = l_red[0][row][col] + l_red[1][row][col] +
                    l_red[2][row][col] + l_red[3][row][col];
    out[(size_t)(row0 + row) * D_ + d0 + col] = v;
  }
}

extern "C" void kernel_launch(void* const* d_in, const int* in_sizes, int n_in,
                              void* d_out, int out_size, void* d_ws,
                              size_t ws_size, hipStream_t stream) {
  const float* M = (const float*)d_in[0];
  const int* mask = (const int*)d_in[1];
  const float* W1 = (const float*)d_in[2];
  const float* b1 = (const float*)d_in[3];
  const float* W2 = (const float*)d_in[4];
  const float* b2 = (const float*)d_in[5];
  const float* vw = (const float*)d_in[6];
  float* out = (float*)d_out;

  // workspace carve-up: ~18.75 MB total
  float* w1e = (float*)d_ws;                      // [2048][128] f32   1 MB
  float* w2e = w1e + 2048 * A_;                   // [4][128][512]     1 MB
  ushort* ah = (ushort*)(w2e + 4 * A_ * N_);      // [2048][512] bf16  2 MB
  ushort* al = ah + 2048 * N_;                    //                   2 MB
  ushort* Mr_h = al + 2048 * N_;                  // [2048][768] bf16  3 MB
  ushort* Mr_l = Mr_h + 2048 * D_;                //                   3 MB
  ushort* Mt_h = Mr_l + 2048 * D_;                // [4][768][512]     3 MB
  ushort* Mt_l = Mt_h + 2048 * D_;                //                   3 MB
  ushort* Wt_h = Mt_l + 2048 * D_;                // [256][768] bf16   .375
  ushort* Wt_l = Wt_h + 256 * D_;                 //                   .375
  float* uvec = (float*)(Wt_l + 256 * D_);        // [128] f32         512B

  k0_prep<<<864, 256, 0, stream>>>(M, W1, W2, vw, Mr_h, Mr_l, Mt_h, Mt_l,
                                   Wt_h, Wt_l, uvec);
  k1_mfma<<<dim3(2048 / 32, 8), 256, 0, stream>>>(Mr_h, Mr_l, Wt_h, Wt_l,
                                                  b1, b2, w1e, w2e);
  k2_scores<<<(B_ * N_) / 8, 512, 0, stream>>>(w1e, w2e, uvec, mask, vw,
                                               ah, al);
  k3_mfma<<<dim3(2048 / 64, D_ / 32), 256, 0, stream>>>(ah, al, Mt_h, Mt_l,
                                                        out);
}

// Round 15
// 69.951 us; speedup vs baseline: 6.9888x; 1.1412x over previous
//
#include <hip/hip_runtime.h>

#define B_ 4
#define N_ 512
#define D_ 768
#define A_ 128

typedef short bf16x8 __attribute__((ext_vector_type(8)));
typedef ushort u16x8 __attribute__((ext_vector_type(8)));
typedef ushort u16x4 __attribute__((ext_vector_type(4)));
typedef float f32x4 __attribute__((ext_vector_type(4)));

__device__ __forceinline__ ushort f2h(float x) {  // f32 -> bf16 bits, RNE
  uint u = __builtin_bit_cast(uint, x);
  return (ushort)((u + 0x7fffu + ((u >> 16) & 1u)) >> 16);
}
__device__ __forceinline__ float h2f(ushort h) {
  uint u = ((uint)h) << 16;
  return __builtin_bit_cast(float, u);
}
__device__ __forceinline__ bf16x8 ld8(const ushort* p) {
  return *(const bf16x8*)p;
}
#define MFMA(a, b, c) __builtin_amdgcn_mfma_f32_16x16x32_bf16(a, b, c, 0, 0, 0)

// ---------------------------------------------------------------------------
// k0: fused prep (+ uvec = -2*v write). Unchanged from R14.
// ---------------------------------------------------------------------------
__global__ __launch_bounds__(256) void k0_prep(
    const float* __restrict__ M, const float* __restrict__ W1,
    const float* __restrict__ W2, const float* __restrict__ vw,
    ushort* __restrict__ Mr_h, ushort* __restrict__ Mr_l,
    ushort* __restrict__ Mt_h, ushort* __restrict__ Mt_l,
    ushort* __restrict__ Wt_h, ushort* __restrict__ Wt_l,
    float* __restrict__ uvec) {
  __shared__ ushort lds_h[64][40];
  __shared__ ushort lds_l[64][40];
  const int t = threadIdx.x;
  const int bid = blockIdx.x;
  if (bid < 768) {  // ---- M part ----
    const int dq = bid % 12;
    const int rest = bid / 12;
    const int d0 = dq * 64;
    const int n0 = (rest & 15) * 32;
    const int b = rest >> 4;
    const int n = t >> 3;          // 0..31
    const int dg = (t & 7) * 8;    // 0..56
    const size_t roff = ((size_t)(b * N_ + n0 + n)) * D_ + d0 + dg;
    const float4 v0 = *(const float4*)(M + roff);
    const float4 v1 = *(const float4*)(M + roff + 4);
    const float x[8] = {v0.x, v0.y, v0.z, v0.w, v1.x, v1.y, v1.z, v1.w};
    u16x8 vh, vl;
#pragma unroll
    for (int e = 0; e < 8; ++e) {
      ushort h = f2h(x[e]);
      ushort l = f2h(x[e] - h2f(h));
      vh[e] = h;
      vl[e] = l;
      lds_h[dg + e][n] = h;
      lds_l[dg + e][n] = l;
    }
    *(u16x8*)(Mr_h + roff) = vh;
    *(u16x8*)(Mr_l + roff) = vl;
    __syncthreads();
    const int dd = t >> 2;          // 0..63
    const int ng = (t & 3) * 8;     // 0..24
    const size_t toff = ((size_t)b * D_ + d0 + dd) * N_ + n0 + ng;
    *(u16x8*)(Mt_h + toff) = *(const u16x8*)(&lds_h[dd][ng]);
    *(u16x8*)(Mt_l + toff) = *(const u16x8*)(&lds_l[dd][ng]);
  } else {  // ---- W part ----
    const int c = t;
    const int k0 = (bid - 768) * 8;
    const float* __restrict__ Wp = (c < A_) ? W1 : W2;
    const int cc = c & (A_ - 1);
    u16x8 vh, vl;
#pragma unroll
    for (int e = 0; e < 8; ++e) {
      float x = Wp[(size_t)(k0 + e) * A_ + cc];
      ushort h = f2h(x);
      vh[e] = h;
      vl[e] = f2h(x - h2f(h));
    }
    *(u16x8*)(Wt_h + (size_t)c * D_ + k0) = vh;
    *(u16x8*)(Wt_l + (size_t)c * D_ + k0) = vl;
    if (bid == 768 && c < A_) uvec[c] = -2.f * vw[c];
  }
}

// ---------------------------------------------------------------------------
// k1 v3: M @ [W1|W2] -> EXPONENTIALS (unchanged from R14).
// ---------------------------------------------------------------------------
__global__ __launch_bounds__(256) void k1_mfma(
    const ushort* __restrict__ Mr_h, const ushort* __restrict__ Mr_l,
    const ushort* __restrict__ Wt_h, const ushort* __restrict__ Wt_l,
    const float* __restrict__ b1, const float* __restrict__ b2,
    float* __restrict__ w1e, float* __restrict__ w2e) {
  __shared__ float l_red[4][32][33];  // 16.9 KB
  const int t = threadIdx.x;
  const int l = t & 63;
  const int w = t >> 6;
  const int r = l & 15, g = l >> 4;
  const int row0 = blockIdx.x * 32;
  const int cb = blockIdx.y * 32;
  const int kbase = w * 192;  // wave-private K-range (6 K-steps of 32)
  const size_t oA = (size_t)(row0 + r) * D_ + kbase + g * 8;
  const size_t oA2 = oA + (size_t)16 * D_;
  const size_t oB = (size_t)(cb + r) * D_ + kbase + g * 8;
  const size_t oB2 = oB + (size_t)16 * D_;
  f32x4 acc[2][2] = {};
  bf16x8 A[2][4], Bv[2][4];
#define K1LOAD(s, k0)                                                        \
  A[s][0] = ld8(Mr_h + oA + (k0));  A[s][1] = ld8(Mr_h + oA2 + (k0));        \
  A[s][2] = ld8(Mr_l + oA + (k0));  A[s][3] = ld8(Mr_l + oA2 + (k0));        \
  Bv[s][0] = ld8(Wt_h + oB + (k0)); Bv[s][1] = ld8(Wt_h + oB2 + (k0));       \
  Bv[s][2] = ld8(Wt_l + oB + (k0)); Bv[s][3] = ld8(Wt_l + oB2 + (k0));
#define K1MM(s)                                                              \
  acc[0][0] = MFMA(A[s][0], Bv[s][0], acc[0][0]);                            \
  acc[0][0] = MFMA(A[s][0], Bv[s][2], acc[0][0]);                            \
  acc[0][0] = MFMA(A[s][2], Bv[s][0], acc[0][0]);                            \
  acc[0][1] = MFMA(A[s][0], Bv[s][1], acc[0][1]);                            \
  acc[0][1] = MFMA(A[s][0], Bv[s][3], acc[0][1]);                            \
  acc[0][1] = MFMA(A[s][2], Bv[s][1], acc[0][1]);                            \
  acc[1][0] = MFMA(A[s][1], Bv[s][0], acc[1][0]);                            \
  acc[1][0] = MFMA(A[s][1], Bv[s][2], acc[1][0]);                            \
  acc[1][0] = MFMA(A[s][3], Bv[s][0], acc[1][0]);                            \
  acc[1][1] = MFMA(A[s][1], Bv[s][1], acc[1][1]);                            \
  acc[1][1] = MFMA(A[s][1], Bv[s][3], acc[1][1]);                            \
  acc[1][1] = MFMA(A[s][3], Bv[s][1], acc[1][1]);
  K1LOAD(0, 0)
#pragma unroll
  for (int kt = 0; kt < 6; ++kt) {
    if (kt & 1) {
      if (kt < 5) { K1LOAD(0, (kt + 1) * 32) }
      K1MM(1)
    } else {
      if (kt < 5) { K1LOAD(1, (kt + 1) * 32) }
      K1MM(0)
    }
  }
#undef K1LOAD
#undef K1MM
#pragma unroll
  for (int fi = 0; fi < 2; ++fi)
#pragma unroll
    for (int fj = 0; fj < 2; ++fj)
#pragma unroll
      for (int rr = 0; rr < 4; ++rr)
        l_red[w][fi * 16 + g * 4 + rr][fj * 16 + r] = acc[fi][fj][rr];
  __syncthreads();

  const float SC = 2.8853900817779268f;  // 2*log2(e): e^{2x} = 2^{SC*x}
  const int b = row0 >> 9;
  const int n0 = row0 & (N_ - 1);
  if (cb < A_) {  // E1: w1e[row][col], col-fast coalesced
#pragma unroll
    for (int k = 0; k < 4; ++k) {
      const int row = (t >> 5) + k * 8;
      const int col = t & 31;
      float v = l_red[0][row][col] + l_red[1][row][col] +
                l_red[2][row][col] + l_red[3][row][col];
      v = (v + b1[cb + col]) * SC;
      w1e[(size_t)(row0 + row) * A_ + cb + col] = __builtin_amdgcn_exp2f(v);
    }
  } else {  // E2: w2e[(b*128 + a)*512 + n], row(n)-fast coalesced
#pragma unroll
    for (int k = 0; k < 4; ++k) {
      const int row = t & 31;
      const int col = (t >> 5) + k * 8;
      float v = l_red[0][row][col] + l_red[1][row][col] +
                l_red[2][row][col] + l_red[3][row][col];
      v = (v + b2[cb - A_ + col]) * SC;
      w2e[(size_t)(b * A_ + cb - A_ + col) * N_ + n0 + row] =
          __builtin_amdgcn_exp2f(v);
    }
  }
}

// ---------------------------------------------------------------------------
// k2 v15: OCCUPANCY FIX — 1024-thread blocks, 16 waves = 8 rows x 2
// j-halves (4 waves/SIMD, was 2: every prior variant was latency-stall-
// bound at 2). Wave owns 256 j of one row -> 4 j/lane, one float4 acc.
// Same [2][16][512] 64KB dbuf tile + T14 staging (traffic unchanged).
// E1/u via readfirstlane + scalar loads. b128 LDS reads (lane*16B,
// conflict-free). Cross-half softmax merge via tiny LDS.
// ---------------------------------------------------------------------------
__global__ __launch_bounds__(1024) void k2_scores(
    const float* __restrict__ w1e, const float* __restrict__ w2e,
    const float* __restrict__ uvec, const int* __restrict__ mask,
    const float* __restrict__ vw, ushort* __restrict__ ah,
    ushort* __restrict__ al) {
  __shared__ float l_w2[2][16][N_];  // 64 KB: [buf][a_local][j]
  __shared__ float l_red[8][2];
  __shared__ float l_sum[8][2];
  const int t = threadIdx.x;
  const int lane = t & 63;
  const int w = t >> 6;   // 0..15
  const int r = w >> 1;   // row in block 0..7
  const int h = w & 1;    // j-half
  const int i0 = blockIdx.x * 8;
  const int b = i0 >> 9;
  const int i = i0 + r;
  const int iu = __builtin_amdgcn_readfirstlane(i);
  const float* __restrict__ w1row = w1e + (size_t)iu * A_;  // scalar loads

  float vs = vw[lane] + vw[64 + lane];  // Vsum via butterfly
#pragma unroll
  for (int off = 32; off; off >>= 1) vs += __shfl_xor(vs, off);

  const float* __restrict__ w2src = w2e + (size_t)b * A_ * N_;
  float4 st[2];  // staging: tile = 16 a x 512 j = 2048 f4 / 1024 thr

#define STAGE_LOAD(cc)                                                      \
  {                                                                         \
    const float* __restrict__ src = w2src + (size_t)(cc) * 16 * N_;         \
    _Pragma("unroll") for (int k = 0; k < 2; ++k) {                         \
      const int f = t + k * 1024;                                           \
      st[k] = *(const float4*)(src + (size_t)(f >> 7) * N_ + (f & 127) * 4);\
    }                                                                       \
  }
#define STAGE_WRITE(bf)                                                     \
  {                                                                         \
    _Pragma("unroll") for (int k = 0; k < 2; ++k) {                         \
      const int f = t + k * 1024;                                           \
      *(float4*)(&l_w2[bf][f >> 7][(f & 127) * 4]) = st[k];                 \
    }                                                                       \
  }

  STAGE_LOAD(0)
  STAGE_WRITE(0)
  __syncthreads();

  const int jb = h * 256 + lane * 4;  // this lane's 4 j columns
  float4 s = {0.f, 0.f, 0.f, 0.f};
#pragma unroll 1
  for (int cc = 0; cc < 8; ++cc) {
    if (cc + 1 < 8) STAGE_LOAD(cc + 1)  // issue early (T14)
    const float(*wb)[N_] = l_w2[cc & 1];
#pragma unroll 1
    for (int aa = 0; aa < 4; ++aa) {
      const float4 wa = *(const float4*)(w1row + cc * 16 + aa * 4);  // s_load
      const float4 uu = *(const float4*)(uvec + cc * 16 + aa * 4);   // s_load
      const float wa_[4] = {wa.x, wa.y, wa.z, wa.w};
      const float uu_[4] = {uu.x, uu.y, uu.z, uu.w};
#pragma unroll
      for (int e = 0; e < 4; ++e) {
        const float wx = wa_[e];
        const float ux = uu_[e];
        const float4 x = *(const float4*)(&wb[aa * 4 + e][jb]);
        s.x = fmaf(ux, __builtin_amdgcn_rcpf(fmaf(wx, x.x, 1.f)), s.x);
        s.y = fmaf(ux, __builtin_amdgcn_rcpf(fmaf(wx, x.y, 1.f)), s.y);
        s.z = fmaf(ux, __builtin_amdgcn_rcpf(fmaf(wx, x.z, 1.f)), s.z);
        s.w = fmaf(ux, __builtin_amdgcn_rcpf(fmaf(wx, x.w, 1.f)), s.w);
      }
    }
    if (cc + 1 < 8) { STAGE_WRITE((cc + 1) & 1) }  // write late (T14)
    __syncthreads();
  }
#undef STAGE_LOAD
#undef STAGE_WRITE

  // masks (coalesced int4), then scores
  const float NEG = -3.402823466e38f;  // np.finfo(f32).min
  const int4 mk = *(const int4*)(mask + (size_t)i * N_ + jb);
  s.x = mk.x ? (vs + s.x) : NEG;
  s.y = mk.y ? (vs + s.y) : NEG;
  s.z = mk.z ? (vs + s.z) : NEG;
  s.w = mk.w ? (vs + s.w) : NEG;

  // softmax: wave-local max -> cross-half merge via LDS
  float rmax = fmaxf(fmaxf(s.x, s.y), fmaxf(s.z, s.w));
#pragma unroll
  for (int off = 32; off; off >>= 1) rmax = fmaxf(rmax, __shfl_xor(rmax, off));
  if (lane == 0) l_red[r][h] = rmax;
  __syncthreads();
  rmax = fmaxf(l_red[r][0], l_red[r][1]);

  const float L2E = 1.4426950408889634f;
  // all-masked row: s-rmax = 0 -> 1 -> uniform 1/512 (ref match);
  // masked in live row: (NEG-rmax)*L2E -> -inf -> exp2 = 0 exactly.
  s.x = __builtin_amdgcn_exp2f((s.x - rmax) * L2E);
  s.y = __builtin_amdgcn_exp2f((s.y - rmax) * L2E);
  s.z = __builtin_amdgcn_exp2f((s.z - rmax) * L2E);
  s.w = __builtin_amdgcn_exp2f((s.w - rmax) * L2E);
  float psum = (s.x + s.y) + (s.z + s.w);
#pragma unroll
  for (int off = 32; off; off >>= 1) psum += __shfl_xor(psum, off);
  if (lane == 0) l_sum[r][h] = psum;
  __syncthreads();
  const float inv = __builtin_amdgcn_rcpf(l_sum[r][0] + l_sum[r][1]);

  const float p[4] = {s.x * inv, s.y * inv, s.z * inv, s.w * inv};
  u16x4 vh, vl;
#pragma unroll
  for (int e = 0; e < 4; ++e) {
    const ushort hh = f2h(p[e]);
    vh[e] = hh;
    vl[e] = f2h(p[e] - h2f(hh));
  }
  *(u16x4*)(ah + (size_t)i * N_ + jb) = vh;
  *(u16x4*)(al + (size_t)i * N_ + jb) = vl;
}

// ---------------------------------------------------------------------------
// k3 v4: out[b] = attn[b] @ M[b] (unchanged from R14).
// ---------------------------------------------------------------------------
__global__ __launch_bounds__(256) void k3_mfma(
    const ushort* __restrict__ ah, const ushort* __restrict__ al,
    const ushort* __restrict__ Mt_h, const ushort* __restrict__ Mt_l,
    float* __restrict__ out) {
  __shared__ float l_red[4][64][33];  // 33.8 KB
  const int t = threadIdx.x;
  const int l = t & 63;
  const int w = t >> 6;
  const int r = l & 15, g = l >> 4;
  const int row0 = blockIdx.x * 64;    // global row b*N+i (64 | 512)
  const int d0 = blockIdx.y * 32;
  const int b = row0 >> 9;
  const int jbase = w * 128;  // wave-private j-range (4 K-steps of 32)
  const ushort* __restrict__ Bh = Mt_h + (size_t)b * D_ * N_;
  const ushort* __restrict__ Bl = Mt_l + (size_t)b * D_ * N_;
  size_t oA[4];
#pragma unroll
  for (int fi = 0; fi < 4; ++fi)
    oA[fi] = (size_t)(row0 + fi * 16 + r) * N_ + jbase + g * 8;
  const size_t oB = (size_t)(d0 + r) * N_ + jbase + g * 8;
  const size_t oB2 = oB + (size_t)16 * N_;
  f32x4 acc[4][2] = {};
  bf16x8 A[2][8], Bv[2][4];
#define K3LOAD(s, j0)                                                        \
  A[s][0] = ld8(ah + oA[0] + (j0)); A[s][1] = ld8(ah + oA[1] + (j0));        \
  A[s][2] = ld8(ah + oA[2] + (j0)); A[s][3] = ld8(ah + oA[3] + (j0));        \
  A[s][4] = ld8(al + oA[0] + (j0)); A[s][5] = ld8(al + oA[1] + (j0));        \
  A[s][6] = ld8(al + oA[2] + (j0)); A[s][7] = ld8(al + oA[3] + (j0));        \
  Bv[s][0] = ld8(Bh + oB + (j0));   Bv[s][1] = ld8(Bh + oB2 + (j0));         \
  Bv[s][2] = ld8(Bl + oB + (j0));   Bv[s][3] = ld8(Bl + oB2 + (j0));
#define K3MM(s)                                                              \
  _Pragma("unroll") for (int fi = 0; fi < 4; ++fi)                           \
  _Pragma("unroll") for (int fd = 0; fd < 2; ++fd) {                         \
    acc[fi][fd] = MFMA(A[s][fi], Bv[s][fd], acc[fi][fd]);                    \
    acc[fi][fd] = MFMA(A[s][fi], Bv[s][fd + 2], acc[fi][fd]);                \
    acc[fi][fd] = MFMA(A[s][fi + 4], Bv[s][fd], acc[fi][fd]);                \
  }
  K3LOAD(0, 0)
#pragma unroll
  for (int kt = 0; kt < 4; ++kt) {
    if (kt & 1) {
      if (kt < 3) { K3LOAD(0, (kt + 1) * 32) }
      K3MM(1)
    } else {
      if (kt < 3) { K3LOAD(1, (kt + 1) * 32) }
      K3MM(0)
    }
  }
#undef K3LOAD
#undef K3MM
#pragma unroll
  for (int fi = 0; fi < 4; ++fi)
#pragma unroll
    for (int fd = 0; fd < 2; ++fd)
#pragma unroll
      for (int rr = 0; rr < 4; ++rr)
        l_red[w][fi * 16 + g * 4 + rr][fd * 16 + r] = acc[fi][fd][rr];
  __syncthreads();
#pragma unroll
  for (int k = 0; k < 8; ++k) {
    const int row = (t >> 5) + k * 8;
    const int col = t & 31;
    const float v = l_red[0][row][col] + l_red[1][row][col] +
                    l_red[2][row][col] + l_red[3][row][col];
    out[(size_t)(row0 + row) * D_ + d0 + col] = v;
  }
}

extern "C" void kernel_launch(void* const* d_in, const int* in_sizes, int n_in,
                              void* d_out, int out_size, void* d_ws,
                              size_t ws_size, hipStream_t stream) {
  const float* M = (const float*)d_in[0];
  const int* mask = (const int*)d_in[1];
  const float* W1 = (const float*)d_in[2];
  const float* b1 = (const float*)d_in[3];
  const float* W2 = (const float*)d_in[4];
  const float* b2 = (const float*)d_in[5];
  const float* vw = (const float*)d_in[6];
  float* out = (float*)d_out;

  // workspace carve-up: ~18.75 MB total
  float* w1e = (float*)d_ws;                      // [2048][128] f32   1 MB
  float* w2e = w1e + 2048 * A_;                   // [4][128][512]     1 MB
  ushort* ah = (ushort*)(w2e + 4 * A_ * N_);      // [2048][512] bf16  2 MB
  ushort* al = ah + 2048 * N_;                    //                   2 MB
  ushort* Mr_h = al + 2048 * N_;                  // [2048][768] bf16  3 MB
  ushort* Mr_l = Mr_h + 2048 * D_;                //                   3 MB
  ushort* Mt_h = Mr_l + 2048 * D_;                // [4][768][512]     3 MB
  ushort* Mt_l = Mt_h + 2048 * D_;                //                   3 MB
  ushort* Wt_h = Mt_l + 2048 * D_;                // [256][768] bf16   .375
  ushort* Wt_l = Wt_h + 256 * D_;                 //                   .375
  float* uvec = (float*)(Wt_l + 256 * D_);        // [128] f32         512B

  k0_prep<<<864, 256, 0, stream>>>(M, W1, W2, vw, Mr_h, Mr_l, Mt_h, Mt_l,
                                   Wt_h, Wt_l, uvec);
  k1_mfma<<<dim3(2048 / 32, 8), 256, 0, stream>>>(Mr_h, Mr_l, Wt_h, Wt_l,
                                                  b1, b2, w1e, w2e);
  k2_scores<<<(B_ * N_) / 8, 1024, 0, stream>>>(w1e, w2e, uvec, mask, vw,
                                                ah, al);
  k3_mfma<<<dim3(2048 / 64, D_ / 32), 256, 0, stream>>>(ah, al, Mt_h, Mt_l,
                                                        out);
}

// Round 16
// 66.986 us; speedup vs baseline: 7.2982x; 1.0443x over previous
//
#include <hip/hip_runtime.h>

#define B_ 4
#define N_ 512
#define D_ 768
#define A_ 128

typedef short bf16x8 __attribute__((ext_vector_type(8)));
typedef ushort u16x8 __attribute__((ext_vector_type(8)));
typedef ushort u16x4 __attribute__((ext_vector_type(4)));
typedef float f32x4 __attribute__((ext_vector_type(4)));

__device__ __forceinline__ ushort f2h(float x) {  // f32 -> bf16 bits, RNE
  uint u = __builtin_bit_cast(uint, x);
  return (ushort)((u + 0x7fffu + ((u >> 16) & 1u)) >> 16);
}
__device__ __forceinline__ float h2f(ushort h) {
  uint u = ((uint)h) << 16;
  return __builtin_bit_cast(float, u);
}
__device__ __forceinline__ bf16x8 ld8(const ushort* p) {
  return *(const bf16x8*)p;
}
#define MFMA(a, b, c) __builtin_amdgcn_mfma_f32_16x16x32_bf16(a, b, c, 0, 0, 0)

// ---------------------------------------------------------------------------
// k0: fused prep (+ uvec = -2*v write). Unchanged from R15.
// ---------------------------------------------------------------------------
__global__ __launch_bounds__(256) void k0_prep(
    const float* __restrict__ M, const float* __restrict__ W1,
    const float* __restrict__ W2, const float* __restrict__ vw,
    ushort* __restrict__ Mr_h, ushort* __restrict__ Mr_l,
    ushort* __restrict__ Mt_h, ushort* __restrict__ Mt_l,
    ushort* __restrict__ Wt_h, ushort* __restrict__ Wt_l,
    float* __restrict__ uvec) {
  __shared__ ushort lds_h[64][40];
  __shared__ ushort lds_l[64][40];
  const int t = threadIdx.x;
  const int bid = blockIdx.x;
  if (bid < 768) {  // ---- M part ----
    const int dq = bid % 12;
    const int rest = bid / 12;
    const int d0 = dq * 64;
    const int n0 = (rest & 15) * 32;
    const int b = rest >> 4;
    const int n = t >> 3;          // 0..31
    const int dg = (t & 7) * 8;    // 0..56
    const size_t roff = ((size_t)(b * N_ + n0 + n)) * D_ + d0 + dg;
    const float4 v0 = *(const float4*)(M + roff);
    const float4 v1 = *(const float4*)(M + roff + 4);
    const float x[8] = {v0.x, v0.y, v0.z, v0.w, v1.x, v1.y, v1.z, v1.w};
    u16x8 vh, vl;
#pragma unroll
    for (int e = 0; e < 8; ++e) {
      ushort h = f2h(x[e]);
      ushort l = f2h(x[e] - h2f(h));
      vh[e] = h;
      vl[e] = l;
      lds_h[dg + e][n] = h;
      lds_l[dg + e][n] = l;
    }
    *(u16x8*)(Mr_h + roff) = vh;
    *(u16x8*)(Mr_l + roff) = vl;
    __syncthreads();
    const int dd = t >> 2;          // 0..63
    const int ng = (t & 3) * 8;     // 0..24
    const size_t toff = ((size_t)b * D_ + d0 + dd) * N_ + n0 + ng;
    *(u16x8*)(Mt_h + toff) = *(const u16x8*)(&lds_h[dd][ng]);
    *(u16x8*)(Mt_l + toff) = *(const u16x8*)(&lds_l[dd][ng]);
  } else {  // ---- W part ----
    const int c = t;
    const int k0 = (bid - 768) * 8;
    const float* __restrict__ Wp = (c < A_) ? W1 : W2;
    const int cc = c & (A_ - 1);
    u16x8 vh, vl;
#pragma unroll
    for (int e = 0; e < 8; ++e) {
      float x = Wp[(size_t)(k0 + e) * A_ + cc];
      ushort h = f2h(x);
      vh[e] = h;
      vl[e] = f2h(x - h2f(h));
    }
    *(u16x8*)(Wt_h + (size_t)c * D_ + k0) = vh;
    *(u16x8*)(Wt_l + (size_t)c * D_ + k0) = vl;
    if (bid == 768 && c < A_) uvec[c] = -2.f * vw[c];
  }
}

// ---------------------------------------------------------------------------
// k1 v4: M @ [W1|W2] -> EXPONENTIALS. Same GEMM as R15; epilogue now writes
// E2 as bf16 (w2e ushort [b][a][512]) to halve k2's LDS/global traffic.
// E1 stays f32 (scalar-load path in k2).
// ---------------------------------------------------------------------------
__global__ __launch_bounds__(256) void k1_mfma(
    const ushort* __restrict__ Mr_h, const ushort* __restrict__ Mr_l,
    const ushort* __restrict__ Wt_h, const ushort* __restrict__ Wt_l,
    const float* __restrict__ b1, const float* __restrict__ b2,
    float* __restrict__ w1e, ushort* __restrict__ w2e) {
  __shared__ float l_red[4][32][33];  // 16.9 KB
  const int t = threadIdx.x;
  const int l = t & 63;
  const int w = t >> 6;
  const int r = l & 15, g = l >> 4;
  const int row0 = blockIdx.x * 32;
  const int cb = blockIdx.y * 32;
  const int kbase = w * 192;  // wave-private K-range (6 K-steps of 32)
  const size_t oA = (size_t)(row0 + r) * D_ + kbase + g * 8;
  const size_t oA2 = oA + (size_t)16 * D_;
  const size_t oB = (size_t)(cb + r) * D_ + kbase + g * 8;
  const size_t oB2 = oB + (size_t)16 * D_;
  f32x4 acc[2][2] = {};
  bf16x8 A[2][4], Bv[2][4];
#define K1LOAD(s, k0)                                                        \
  A[s][0] = ld8(Mr_h + oA + (k0));  A[s][1] = ld8(Mr_h + oA2 + (k0));        \
  A[s][2] = ld8(Mr_l + oA + (k0));  A[s][3] = ld8(Mr_l + oA2 + (k0));        \
  Bv[s][0] = ld8(Wt_h + oB + (k0)); Bv[s][1] = ld8(Wt_h + oB2 + (k0));       \
  Bv[s][2] = ld8(Wt_l + oB + (k0)); Bv[s][3] = ld8(Wt_l + oB2 + (k0));
#define K1MM(s)                                                              \
  acc[0][0] = MFMA(A[s][0], Bv[s][0], acc[0][0]);                            \
  acc[0][0] = MFMA(A[s][0], Bv[s][2], acc[0][0]);                            \
  acc[0][0] = MFMA(A[s][2], Bv[s][0], acc[0][0]);                            \
  acc[0][1] = MFMA(A[s][0], Bv[s][1], acc[0][1]);                            \
  acc[0][1] = MFMA(A[s][0], Bv[s][3], acc[0][1]);                            \
  acc[0][1] = MFMA(A[s][2], Bv[s][1], acc[0][1]);                            \
  acc[1][0] = MFMA(A[s][1], Bv[s][0], acc[1][0]);                            \
  acc[1][0] = MFMA(A[s][1], Bv[s][2], acc[1][0]);                            \
  acc[1][0] = MFMA(A[s][3], Bv[s][0], acc[1][0]);                            \
  acc[1][1] = MFMA(A[s][1], Bv[s][1], acc[1][1]);                            \
  acc[1][1] = MFMA(A[s][1], Bv[s][3], acc[1][1]);                            \
  acc[1][1] = MFMA(A[s][3], Bv[s][1], acc[1][1]);
  K1LOAD(0, 0)
#pragma unroll
  for (int kt = 0; kt < 6; ++kt) {
    if (kt & 1) {
      if (kt < 5) { K1LOAD(0, (kt + 1) * 32) }
      K1MM(1)
    } else {
      if (kt < 5) { K1LOAD(1, (kt + 1) * 32) }
      K1MM(0)
    }
  }
#undef K1LOAD
#undef K1MM
#pragma unroll
  for (int fi = 0; fi < 2; ++fi)
#pragma unroll
    for (int fj = 0; fj < 2; ++fj)
#pragma unroll
      for (int rr = 0; rr < 4; ++rr)
        l_red[w][fi * 16 + g * 4 + rr][fj * 16 + r] = acc[fi][fj][rr];
  __syncthreads();

  const float SC = 2.8853900817779268f;  // 2*log2(e): e^{2x} = 2^{SC*x}
  const int b = row0 >> 9;
  const int n0 = row0 & (N_ - 1);
  if (cb < A_) {  // E1: w1e[row][col] f32, col-fast coalesced
#pragma unroll
    for (int k = 0; k < 4; ++k) {
      const int row = (t >> 5) + k * 8;
      const int col = t & 31;
      float v = l_red[0][row][col] + l_red[1][row][col] +
                l_red[2][row][col] + l_red[3][row][col];
      v = (v + b1[cb + col]) * SC;
      w1e[(size_t)(row0 + row) * A_ + cb + col] = __builtin_amdgcn_exp2f(v);
    }
  } else {  // E2: w2e[(b*128 + a)*512 + n] BF16, row(n)-fast
#pragma unroll
    for (int k = 0; k < 4; ++k) {
      const int row = t & 31;
      const int col = (t >> 5) + k * 8;
      float v = l_red[0][row][col] + l_red[1][row][col] +
                l_red[2][row][col] + l_red[3][row][col];
      v = (v + b2[cb - A_ + col]) * SC;
      w2e[(size_t)(b * A_ + cb - A_ + col) * N_ + n0 + row] =
          f2h(__builtin_amdgcn_exp2f(v));
    }
  }
}

// ---------------------------------------------------------------------------
// k2 v16: bf16 E2 + more blocks. Block = 512 thr = 8 waves = 4 rows x 2
// j-halves; grid 512 -> 2 blocks/CU (16 waves/CU). LDS tile [2][16][512]
// bf16 = 32 KB (half of v15's bytes on the LDS pipe). Lane owns 4 j:
// ds_read_b64 (u16x4) + h2f. E1/u via readfirstlane scalar loads.
// Per elem: {h2f, fma, rcp, fma}. T14 staging, unroll 1 on cc/aa.
// Cross-half softmax merge via tiny LDS (as v15).
// ---------------------------------------------------------------------------
__global__ __launch_bounds__(512) void k2_scores(
    const float* __restrict__ w1e, const ushort* __restrict__ w2e,
    const float* __restrict__ uvec, const int* __restrict__ mask,
    const float* __restrict__ vw, ushort* __restrict__ ah,
    ushort* __restrict__ al) {
  __shared__ ushort l_w2[2][16][N_];  // 32 KB: [buf][a_local][j] bf16
  __shared__ float l_red[4][2];
  __shared__ float l_sum[4][2];
  const int t = threadIdx.x;
  const int lane = t & 63;
  const int w = t >> 6;   // 0..7
  const int r = w >> 1;   // row in block 0..3
  const int h = w & 1;    // j-half
  const int i0 = blockIdx.x * 4;
  const int b = i0 >> 9;
  const int i = i0 + r;
  const int iu = __builtin_amdgcn_readfirstlane(i);
  const float* __restrict__ w1row = w1e + (size_t)iu * A_;  // scalar loads

  float vs = vw[lane] + vw[64 + lane];  // Vsum via butterfly
#pragma unroll
  for (int off = 32; off; off >>= 1) vs += __shfl_xor(vs, off);

  const ushort* __restrict__ w2src = w2e + (size_t)b * A_ * N_;
  u16x8 st[2];  // staging: tile = 16 a x 512 j bf16 = 1024 x 16B / 512 thr

#define STAGE_LOAD(cc)                                                      \
  {                                                                         \
    const ushort* __restrict__ src = w2src + (size_t)(cc) * 16 * N_;        \
    _Pragma("unroll") for (int k = 0; k < 2; ++k) {                         \
      const int f = t + k * 512;                                            \
      st[k] = *(const u16x8*)(src + (size_t)(f >> 6) * N_ + (f & 63) * 8);  \
    }                                                                       \
  }
#define STAGE_WRITE(bf)                                                     \
  {                                                                         \
    _Pragma("unroll") for (int k = 0; k < 2; ++k) {                         \
      const int f = t + k * 512;                                            \
      *(u16x8*)(&l_w2[bf][f >> 6][(f & 63) * 8]) = st[k];                   \
    }                                                                       \
  }

  STAGE_LOAD(0)
  STAGE_WRITE(0)
  __syncthreads();

  const int jb = h * 256 + lane * 4;  // this lane's 4 j columns
  float4 s = {0.f, 0.f, 0.f, 0.f};
#pragma unroll 1
  for (int cc = 0; cc < 8; ++cc) {
    if (cc + 1 < 8) STAGE_LOAD(cc + 1)  // issue early (T14)
    const ushort(*wb)[N_] = l_w2[cc & 1];
#pragma unroll 1
    for (int aa = 0; aa < 4; ++aa) {
      const float4 wa = *(const float4*)(w1row + cc * 16 + aa * 4);  // s_load
      const float4 uu = *(const float4*)(uvec + cc * 16 + aa * 4);   // s_load
      const float wa_[4] = {wa.x, wa.y, wa.z, wa.w};
      const float uu_[4] = {uu.x, uu.y, uu.z, uu.w};
#pragma unroll
      for (int e = 0; e < 4; ++e) {
        const float wx = wa_[e];
        const float ux = uu_[e];
        const u16x4 xr = *(const u16x4*)(&wb[aa * 4 + e][jb]);  // b64
        s.x = fmaf(ux, __builtin_amdgcn_rcpf(fmaf(wx, h2f(xr[0]), 1.f)), s.x);
        s.y = fmaf(ux, __builtin_amdgcn_rcpf(fmaf(wx, h2f(xr[1]), 1.f)), s.y);
        s.z = fmaf(ux, __builtin_amdgcn_rcpf(fmaf(wx, h2f(xr[2]), 1.f)), s.z);
        s.w = fmaf(ux, __builtin_amdgcn_rcpf(fmaf(wx, h2f(xr[3]), 1.f)), s.w);
      }
    }
    if (cc + 1 < 8) { STAGE_WRITE((cc + 1) & 1) }  // write late (T14)
    __syncthreads();
  }
#undef STAGE_LOAD
#undef STAGE_WRITE

  // masks (coalesced int4), then scores
  const float NEG = -3.402823466e38f;  // np.finfo(f32).min
  const int4 mk = *(const int4*)(mask + (size_t)i * N_ + jb);
  s.x = mk.x ? (vs + s.x) : NEG;
  s.y = mk.y ? (vs + s.y) : NEG;
  s.z = mk.z ? (vs + s.z) : NEG;
  s.w = mk.w ? (vs + s.w) : NEG;

  // softmax: wave-local max -> cross-half merge via LDS
  float rmax = fmaxf(fmaxf(s.x, s.y), fmaxf(s.z, s.w));
#pragma unroll
  for (int off = 32; off; off >>= 1) rmax = fmaxf(rmax, __shfl_xor(rmax, off));
  if (lane == 0) l_red[r][h] = rmax;
  __syncthreads();
  rmax = fmaxf(l_red[r][0], l_red[r][1]);

  const float L2E = 1.4426950408889634f;
  // all-masked row: s-rmax = 0 -> 1 -> uniform 1/512 (ref match);
  // masked in live row: (NEG-rmax)*L2E -> -inf -> exp2 = 0 exactly.
  s.x = __builtin_amdgcn_exp2f((s.x - rmax) * L2E);
  s.y = __builtin_amdgcn_exp2f((s.y - rmax) * L2E);
  s.z = __builtin_amdgcn_exp2f((s.z - rmax) * L2E);
  s.w = __builtin_amdgcn_exp2f((s.w - rmax) * L2E);
  float psum = (s.x + s.y) + (s.z + s.w);
#pragma unroll
  for (int off = 32; off; off >>= 1) psum += __shfl_xor(psum, off);
  if (lane == 0) l_sum[r][h] = psum;
  __syncthreads();
  const float inv = __builtin_amdgcn_rcpf(l_sum[r][0] + l_sum[r][1]);

  const float p[4] = {s.x * inv, s.y * inv, s.z * inv, s.w * inv};
  u16x4 vh, vl;
#pragma unroll
  for (int e = 0; e < 4; ++e) {
    const ushort hh = f2h(p[e]);
    vh[e] = hh;
    vl[e] = f2h(p[e] - h2f(hh));
  }
  *(u16x4*)(ah + (size_t)i * N_ + jb) = vh;
  *(u16x4*)(al + (size_t)i * N_ + jb) = vl;
}

// ---------------------------------------------------------------------------
// k3 v4: out[b] = attn[b] @ M[b] (unchanged from R15).
// ---------------------------------------------------------------------------
__global__ __launch_bounds__(256) void k3_mfma(
    const ushort* __restrict__ ah, const ushort* __restrict__ al,
    const ushort* __restrict__ Mt_h, const ushort* __restrict__ Mt_l,
    float* __restrict__ out) {
  __shared__ float l_red[4][64][33];  // 33.8 KB
  const int t = threadIdx.x;
  const int l = t & 63;
  const int w = t >> 6;
  const int r = l & 15, g = l >> 4;
  const int row0 = blockIdx.x * 64;    // global row b*N+i (64 | 512)
  const int d0 = blockIdx.y * 32;
  const int b = row0 >> 9;
  const int jbase = w * 128;  // wave-private j-range (4 K-steps of 32)
  const ushort* __restrict__ Bh = Mt_h + (size_t)b * D_ * N_;
  const ushort* __restrict__ Bl = Mt_l + (size_t)b * D_ * N_;
  size_t oA[4];
#pragma unroll
  for (int fi = 0; fi < 4; ++fi)
    oA[fi] = (size_t)(row0 + fi * 16 + r) * N_ + jbase + g * 8;
  const size_t oB = (size_t)(d0 + r) * N_ + jbase + g * 8;
  const size_t oB2 = oB + (size_t)16 * N_;
  f32x4 acc[4][2] = {};
  bf16x8 A[2][8], Bv[2][4];
#define K3LOAD(s, j0)                                                        \
  A[s][0] = ld8(ah + oA[0] + (j0)); A[s][1] = ld8(ah + oA[1] + (j0));        \
  A[s][2] = ld8(ah + oA[2] + (j0)); A[s][3] = ld8(ah + oA[3] + (j0));        \
  A[s][4] = ld8(al + oA[0] + (j0)); A[s][5] = ld8(al + oA[1] + (j0));        \
  A[s][6] = ld8(al + oA[2] + (j0)); A[s][7] = ld8(al + oA[3] + (j0));        \
  Bv[s][0] = ld8(Bh + oB + (j0));   Bv[s][1] = ld8(Bh + oB2 + (j0));         \
  Bv[s][2] = ld8(Bl + oB + (j0));   Bv[s][3] = ld8(Bl + oB2 + (j0));
#define K3MM(s)                                                              \
  _Pragma("unroll") for (int fi = 0; fi < 4; ++fi)                           \
  _Pragma("unroll") for (int fd = 0; fd < 2; ++fd) {                         \
    acc[fi][fd] = MFMA(A[s][fi], Bv[s][fd], acc[fi][fd]);                    \
    acc[fi][fd] = MFMA(A[s][fi], Bv[s][fd + 2], acc[fi][fd]);                \
    acc[fi][fd] = MFMA(A[s][fi + 4], Bv[s][fd], acc[fi][fd]);                \
  }
  K3LOAD(0, 0)
#pragma unroll
  for (int kt = 0; kt < 4; ++kt) {
    if (kt & 1) {
      if (kt < 3) { K3LOAD(0, (kt + 1) * 32) }
      K3MM(1)
    } else {
      if (kt < 3) { K3LOAD(1, (kt + 1) * 32) }
      K3MM(0)
    }
  }
#undef K3LOAD
#undef K3MM
#pragma unroll
  for (int fi = 0; fi < 4; ++fi)
#pragma unroll
    for (int fd = 0; fd < 2; ++fd)
#pragma unroll
      for (int rr = 0; rr < 4; ++rr)
        l_red[w][fi * 16 + g * 4 + rr][fd * 16 + r] = acc[fi][fd][rr];
  __syncthreads();
#pragma unroll
  for (int k = 0; k < 8; ++k) {
    const int row = (t >> 5) + k * 8;
    const int col = t & 31;
    const float v = l_red[0][row][col] + l_red[1][row][col] +
                    l_red[2][row][col] + l_red[3][row][col];
    out[(size_t)(row0 + row) * D_ + d0 + col] = v;
  }
}

extern "C" void kernel_launch(void* const* d_in, const int* in_sizes, int n_in,
                              void* d_out, int out_size, void* d_ws,
                              size_t ws_size, hipStream_t stream) {
  const float* M = (const float*)d_in[0];
  const int* mask = (const int*)d_in[1];
  const float* W1 = (const float*)d_in[2];
  const float* b1 = (const float*)d_in[3];
  const float* W2 = (const float*)d_in[4];
  const float* b2 = (const float*)d_in[5];
  const float* vw = (const float*)d_in[6];
  float* out = (float*)d_out;

  // workspace carve-up: ~18.25 MB total
  float* w1e = (float*)d_ws;                      // [2048][128] f32   1 MB
  ushort* w2eb = (ushort*)(w1e + 2048 * A_);      // [4][128][512] bf16 .5 MB
  ushort* ah = w2eb + 4 * A_ * N_;                // [2048][512] bf16  2 MB
  ushort* al = ah + 2048 * N_;                    //                   2 MB
  ushort* Mr_h = al + 2048 * N_;                  // [2048][768] bf16  3 MB
  ushort* Mr_l = Mr_h + 2048 * D_;                //                   3 MB
  ushort* Mt_h = Mr_l + 2048 * D_;                // [4][768][512]     3 MB
  ushort* Mt_l = Mt_h + 2048 * D_;                //                   3 MB
  ushort* Wt_h = Mt_l + 2048 * D_;                // [256][768] bf16   .375
  ushort* Wt_l = Wt_h + 256 * D_;                 //                   .375
  float* uvec = (float*)(Wt_l + 256 * D_);        // [128] f32         512B

  k0_prep<<<864, 256, 0, stream>>>(M, W1, W2, vw, Mr_h, Mr_l, Mt_h, Mt_l,
                                   Wt_h, Wt_l, uvec);
  k1_mfma<<<dim3(2048 / 32, 8), 256, 0, stream>>>(Mr_h, Mr_l, Wt_h, Wt_l,
                                                  b1, b2, w1e, w2eb);
  k2_scores<<<(B_ * N_) / 4, 512, 0, stream>>>(w1e, w2eb, uvec, mask, vw,
                                               ah, al);
  k3_mfma<<<dim3(2048 / 64, D_ / 32), 256, 0, stream>>>(ah, al, Mt_h, Mt_l,
                                                        out);
}